// Round 13
// baseline (1439.123 us; speedup 1.0000x reference)
//
#include <hip/hip_runtime.h>
#include <hip/hip_fp16.h>
#include <math.h>

// Problem constants
#define NS 4096      // N stocks
#define DIM 512      // D
#define NH 8         // heads
#define HD 64        // head dim
#define M2 4098      // N + 2 nodes
#define MPAD 4224    // m padded to multiple of 32 (264 frags of 16)
#define KKEEP 2048u  // top-k keep

// Output layout (floats): final_out | raw_scores | gate_mean | attn_mean
#define OUT_F 0
#define OUT_R 2097152          // 4096*512
#define OUT_G 18882560         // + 4096*4098
#define OUT_A 18882561

typedef __attribute__((ext_vector_type(8))) short bf16x8;
typedef __attribute__((ext_vector_type(4))) float f32x4;

__device__ __forceinline__ float sigmoidf_(float x) { return 1.0f / (1.0f + __expf(-x)); }

__device__ __forceinline__ unsigned short btrunc(float f) {   // f32 -> bf16 RNE
  unsigned u = __float_as_uint(f);
  u = u + 0x7FFFu + ((u >> 16) & 1u);
  return (unsigned short)(u >> 16);
}
__device__ __forceinline__ float bton(unsigned short h) {
  return __uint_as_float(((unsigned)h) << 16);
}

// wave suffix-scan over 256 bins (4/lane) and rank pick; returns bin + count-strictly-above
__device__ __forceinline__ void scan_pick(unsigned c0, unsigned c1, unsigned c2, unsigned c3,
                                          unsigned k_rem, int lane,
                                          unsigned& bsel_out, unsigned& nxt_out) {
  unsigned run = c0 + c1 + c2 + c3;
  #pragma unroll
  for (int off = 1; off < 64; off <<= 1) {
    unsigned o_ = __shfl_down(run, off, 64);
    if (lane + off < 64) run += o_;
  }
  unsigned s0 = run, s1 = run - c0, s2 = s1 - c1, s3 = s2 - c2, s4 = s3 - c3;
  int which = -1;
  if      (s0 >= k_rem && s1 < k_rem) which = 0;
  else if (s1 >= k_rem && s2 < k_rem) which = 1;
  else if (s2 >= k_rem && s3 < k_rem) which = 2;
  else if (s3 >= k_rem && s4 < k_rem) which = 3;
  unsigned long long bal = __ballot(which >= 0);
  int src = (int)__ffsll(bal) - 1;
  unsigned nxtv = (which == 0) ? s1 : (which == 1) ? s2 : (which == 2) ? s3 : s4;
  unsigned bsel = (unsigned)(4 * lane + (which < 0 ? 0 : which));
  bsel_out = (unsigned)__shfl((int)bsel, src, 64);
  nxt_out  = (unsigned)__shfl((int)nxtv, src, 64);
}

// ---------------- regime_mod = sigmoid([zp,zs] @ Wg.T + bg) ----------------
__global__ __launch_bounds__(256) void regime_kernel(
    const float* __restrict__ zp, const float* __restrict__ zs,
    const float* __restrict__ Wg, const float* __restrict__ bg,
    float* __restrict__ regime) {
  __shared__ float zc[1024];
  int t = threadIdx.x;
  for (int i = t; i < 512; i += 256) { zc[i] = zp[i]; zc[512 + i] = zs[i]; }
  __syncthreads();
  for (int j = t; j < 512; j += 256) {
    const float4* w = (const float4*)(Wg + (size_t)j * 1024);
    float acc = 0.f;
    #pragma unroll 8
    for (int i = 0; i < 256; i++) {
      float4 wv = w[i];
      acc += wv.x * zc[4*i] + wv.y * zc[4*i+1] + wv.z * zc[4*i+2] + wv.w * zc[4*i+3];
    }
    regime[j] = sigmoidf_(acc + bg[j]);
  }
}

// ---------------- generic f32 -> bf16 convert ----------------
__global__ __launch_bounds__(256) void conv_bf(
    const float* __restrict__ src, unsigned short* __restrict__ dst, int n4) {
  int i4 = blockIdx.x * 256 + threadIdx.x;
  if (i4 >= n4) return;
  float4 v = *(const float4*)(src + (size_t)i4 * 4);
  ushort4 o; o.x = btrunc(v.x); o.y = btrunc(v.y); o.z = btrunc(v.z); o.w = btrunc(v.w);
  *(ushort4*)(dst + (size_t)i4 * 4) = o;
}

// ---------------- nodes = concat(zp, zs, sf) in bf16 ----------------
__global__ __launch_bounds__(256) void build_nodes_bf(
    const float* __restrict__ zp, const float* __restrict__ zs,
    const float* __restrict__ sf, unsigned short* __restrict__ nb) {
  int i4 = blockIdx.x * 256 + threadIdx.x;
  if (i4 >= (M2 * DIM) / 4) return;
  int idx = i4 * 4;
  int m = idx >> 9, c = idx & 511;
  const float* src = (m == 0) ? (zp + c) : (m == 1) ? (zs + c)
                               : (sf + (size_t)(m - 2) * 512 + c);
  float4 v = *(const float4*)src;
  ushort4 o; o.x = btrunc(v.x); o.y = btrunc(v.y); o.z = btrunc(v.z); o.w = btrunc(v.w);
  *(ushort4*)(nb + idx) = o;
}

// ---------------- bf16 MFMA GEMM: C = (A[M][K] @ B[N][K]^T * scale + bias) * cscale ----------------
// 128x128 tile, 256 threads (4 waves in 2x2), BK=32.
// mode 0: C fp32 [M][ldc]; mode 1: C bf16 [M][ldc]; mode 2: C bf16 transposed [N][ldc] (C[col][row]).
#define LSTR 40
__global__ __launch_bounds__(256) void gemm_bf16(
    const unsigned short* __restrict__ A, const unsigned short* __restrict__ B,
    const float* __restrict__ bias, const float* __restrict__ cscale,
    float* __restrict__ Cf, unsigned short* __restrict__ Cb,
    int M, int N, int K, int lda, int ldb, int ldc, float scale, int mode) {
  __shared__ unsigned short As[128 * LSTR];
  __shared__ unsigned short Bs[128 * LSTR];
  const int t = threadIdx.x;
  const int w = t >> 6, lane = t & 63;
  const int wr = w >> 1, wc = w & 1;
  const int lr = lane & 15, lg = lane >> 4;
  const int bm = blockIdx.y * 128, bn = blockIdx.x * 128;
  f32x4 acc[4][4] = {};
  for (int k0 = 0; k0 < K; k0 += 32) {
    #pragma unroll
    for (int i = 0; i < 2; i++) {
      int q = t + i * 256;
      int row = q >> 2;
      int ko = (q & 3) * 8;
      bf16x8 av = {};
      int gr = bm + row;
      if (gr < M) av = *(const bf16x8*)(A + (size_t)gr * lda + k0 + ko);
      *(bf16x8*)(As + row * LSTR + ko) = av;
      bf16x8 bv = {};
      int gbr = bn + row;
      if (gbr < N) bv = *(const bf16x8*)(B + (size_t)gbr * ldb + k0 + ko);
      *(bf16x8*)(Bs + row * LSTR + ko) = bv;
    }
    __syncthreads();
    {
      bf16x8 af[4], bfr[4];
      #pragma unroll
      for (int i = 0; i < 4; i++)
        af[i] = *(const bf16x8*)(As + (64 * wr + 16 * i + lr) * LSTR + lg * 8);
      #pragma unroll
      for (int j = 0; j < 4; j++)
        bfr[j] = *(const bf16x8*)(Bs + (64 * wc + 16 * j + lr) * LSTR + lg * 8);
      #pragma unroll
      for (int i = 0; i < 4; i++)
        #pragma unroll
        for (int j = 0; j < 4; j++)
          acc[i][j] = __builtin_amdgcn_mfma_f32_16x16x32_bf16(af[i], bfr[j], acc[i][j], 0, 0, 0);
    }
    __syncthreads();
  }
  // epilogue
  #pragma unroll
  for (int i = 0; i < 4; i++) {
    #pragma unroll
    for (int j = 0; j < 4; j++) {
      #pragma unroll
      for (int q = 0; q < 4; q++) {
        int row = bm + 64 * wr + 16 * i + lg * 4 + q;
        int col = bn + 64 * wc + 16 * j + lr;
        if (row < M && col < N) {
          float v = acc[i][j][q] * scale;
          if (bias)   v += bias[col];
          if (cscale) v *= cscale[col];
          if (mode == 0)      Cf[(size_t)row * ldc + col] = v;
          else if (mode == 1) Cb[(size_t)row * ldc + col] = btrunc(v);
          else                Cb[(size_t)col * ldc + row] = btrunc(v);
        }
      }
    }
  }
}

// ---------------- fused attention ----------------
// 512 blocks (one 8-row tile each, 2/CU for barrier overlap), 512 threads =
// 8 waves, loop h=0..7. Zero persistent per-thread state. Per head:
// ph1: QK^T MFMA (output rows 8-15 discarded) -> S bf16 swizzled LDS.
// ph2 (wave-private, 1 row/wave): pass0 (hi-byte hist + row max), pass1
//   (boundary bin), expA (exp -> LDS + lsum), expB (p=e*invZ -> fp8 Pg).
// ph3: PV MFMA K-split on raw e (A rows clamped to 8), scale invZ; LDS reduce.
#define ROWS 8
#define SROWB 8464                    // 8448 data + 16 pad
#define QOFF  (ROWS * SROWB)          // 67712
#define HOFF  (QOFF + ROWS * 72 * 2)  // + 1152 = 68864
#define SMEMSZ (HOFF + ROWS * 256 * 4) // + 8192 = 77056  -> 2 blocks/CU

__global__ __launch_bounds__(512) void fused_attn(
    const unsigned short* __restrict__ Qbf, const unsigned short* __restrict__ Kbf,
    const unsigned short* __restrict__ Vt, unsigned short* __restrict__ aobf,
    float* __restrict__ attn_mean_out, unsigned char* __restrict__ Pg, int use_pg) {
  extern __shared__ char dsm[];
  unsigned short* qt = (unsigned short*)(dsm + QOFF);
  unsigned* hist = (unsigned*)(dsm + HOFF);    // [8 waves][256], wave-private
  const int n0 = blockIdx.x * ROWS;
  const int t = threadIdx.x;
  const int w = t >> 6, lane = t & 63;
  const int lr = lane & 15, lg = lane >> 4;
  const int lrc = lr & 7;                      // clamped row for 8-row tile
  unsigned* hw = hist + w * 256;
  const int r = w;                              // row owned by this wave (0..7)
  const unsigned swz = (unsigned)(r << 4);

  for (int h = 0; h < NH; ++h) {
    // ---- ph0: Q tile -> LDS (8 x 64, stride 72); one elem per thread ----
    qt[(t >> 6) * 72 + (t & 63)] = Qbf[(size_t)(n0 + (t >> 6)) * DIM + h * HD + (t & 63)];
    __syncthreads();

    // ---- ph1: S = Q @ K^T * 0.125 -> LDS bf16 (swizzled); frag fi = w + 8*f ----
    {
      bf16x8 a0 = *(const bf16x8*)(qt + lrc * 72 + lg * 8);
      bf16x8 a1 = *(const bf16x8*)(qt + lrc * 72 + 32 + lg * 8);
      #pragma unroll
      for (int f = 0; f < 33; ++f) {
        int m0 = (w + 8 * f) * 16;
        const unsigned short* kp = Kbf + (size_t)(m0 + lr) * DIM + h * HD + lg * 8;
        bf16x8 b0 = *(const bf16x8*)(kp);
        bf16x8 b1 = *(const bf16x8*)(kp + 32);
        f32x4 c = {0.f, 0.f, 0.f, 0.f};
        c = __builtin_amdgcn_mfma_f32_16x16x32_bf16(a0, b0, c, 0, 0, 0);
        c = __builtin_amdgcn_mfma_f32_16x16x32_bf16(a1, b1, c, 0, 0, 0);
        int m = m0 + lr;
        #pragma unroll
        for (int q = 0; q < 4; ++q) {
          int rr = lg * 4 + q;
          if (rr < ROWS)
            *(unsigned short*)(dsm + rr * SROWB + ((2 * m) ^ (rr << 4))) = btrunc(c[q] * 0.125f);
        }
      }
    }
    __syncthreads();

    // ---- ph2: select + softmax for row r = w; invZ stays in reg ----
    float invZ;
    {
      // pass 0 sweep: high-byte histogram + fused row max
      unsigned maxkey = 0;
      hw[lane] = 0u; hw[lane + 64] = 0u; hw[lane + 128] = 0u; hw[lane + 192] = 0u;
      #pragma unroll
      for (int c = 0; c < 9; ++c) {
        if (c < 8 || lane < 16) {
          uint4 pk4 = *(const uint4*)(dsm + r * SROWB + (((unsigned)(c * 1024 + lane * 16)) ^ swz));
          const unsigned* pw = (const unsigned*)&pk4;
          #pragma unroll
          for (int p2 = 0; p2 < 4; ++p2) {
            unsigned pk = pw[p2];
            int mb = c * 512 + lane * 8 + p2 * 2;
            #pragma unroll
            for (int e = 0; e < 2; ++e) {
              int m = mb + e;
              unsigned u = (e == 0) ? (pk & 0xFFFFu) : (pk >> 16);
              unsigned key = u ^ ((u & 0x8000u) ? 0xFFFFu : 0x8000u);
              if (m < M2 && key > maxkey) maxkey = key;
              if (m >= 2 && m < M2) atomicAdd(&hw[key >> 8], 1u);
            }
          }
        }
      }
      #pragma unroll
      for (int off = 32; off > 0; off >>= 1) {
        unsigned o_ = (unsigned)__shfl_xor((int)maxkey, off, 64);
        if (o_ > maxkey) maxkey = o_;
      }
      float lmax = bton((unsigned short)(maxkey ^ ((maxkey & 0x8000u) ? 0x8000u : 0xFFFFu)));

      unsigned tb, k_rem = KKEEP;
      {
        unsigned c0 = hw[4*lane], c1 = hw[4*lane+1], c2 = hw[4*lane+2], c3 = hw[4*lane+3];
        unsigned nxtv;
        scan_pick(c0, c1, c2, c3, k_rem, lane, tb, nxtv);
        k_rem -= nxtv;
      }

      // pass 1 sweep: boundary-bin low-byte histogram
      hw[lane] = 0u; hw[lane + 64] = 0u; hw[lane + 128] = 0u; hw[lane + 192] = 0u;
      #pragma unroll
      for (int c = 0; c < 9; ++c) {
        if (c < 8 || lane < 16) {
          uint4 pk4 = *(const uint4*)(dsm + r * SROWB + (((unsigned)(c * 1024 + lane * 16)) ^ swz));
          const unsigned* pw = (const unsigned*)&pk4;
          #pragma unroll
          for (int p2 = 0; p2 < 4; ++p2) {
            unsigned pk = pw[p2];
            int mb = c * 512 + lane * 8 + p2 * 2;
            #pragma unroll
            for (int e = 0; e < 2; ++e) {
              int m = mb + e;
              unsigned u = (e == 0) ? (pk & 0xFFFFu) : (pk >> 16);
              unsigned key = u ^ ((u & 0x8000u) ? 0xFFFFu : 0x8000u);
              if (m >= 2 && m < M2 && (key >> 8) == tb) atomicAdd(&hw[key & 255u], 1u);
            }
          }
        }
      }
      unsigned thrkey;
      {
        unsigned c0 = hw[4*lane], c1 = hw[4*lane+1], c2 = hw[4*lane+2], c3 = hw[4*lane+3];
        unsigned bsel, nxtv;
        scan_pick(c0, c1, c2, c3, k_rem, lane, bsel, nxtv);
        thrkey = (tb << 8) | bsel;
      }

      // expA sweep: e (bf16, rounded) -> LDS in place; lsum of rounded values
      float lsum = 0.f;
      #pragma unroll
      for (int c = 0; c < 9; ++c) {
        if (c < 8 || lane < 16) {
          char* ap = dsm + r * SROWB + (((unsigned)(c * 1024 + lane * 16)) ^ swz);
          uint4 pk4 = *(const uint4*)ap;
          unsigned* pw = (unsigned*)&pk4;
          #pragma unroll
          for (int p2 = 0; p2 < 4; ++p2) {
            unsigned pk = pw[p2];
            int mb = c * 512 + lane * 8 + p2 * 2;
            unsigned outw = 0;
            #pragma unroll
            for (int e = 0; e < 2; ++e) {
              int m = mb + e;
              unsigned u = (e == 0) ? (pk & 0xFFFFu) : (pk >> 16);
              unsigned key = u ^ ((u & 0x8000u) ? 0xFFFFu : 0x8000u);
              bool kept = (m < 2) || (m < M2 && key >= thrkey);
              float evf = kept ? __expf(bton((unsigned short)u) - lmax) : 0.f;
              unsigned short eb = btrunc(evf);
              lsum += bton(eb);
              outw |= ((unsigned)eb) << (16 * e);
            }
            pw[p2] = outw;
          }
          *(uint4*)ap = pk4;
        }
      }
      #pragma unroll
      for (int off = 32; off > 0; off >>= 1) lsum += __shfl_xor(lsum, off, 64);
      invZ = 1.0f / lsum;

      // expB-light: read e from LDS, p = e*invZ -> fp8 Pg (or fp32 RMW fallback)
      #pragma unroll
      for (int c = 0; c < 9; ++c) {
        if (c < 8 || lane < 16) {
          const char* ap = dsm + r * SROWB + (((unsigned)(c * 1024 + lane * 16)) ^ swz);
          uint4 e4 = *(const uint4*)ap;
          const unsigned* pw = (const unsigned*)&e4;
          float pv[8];
          #pragma unroll
          for (int p2 = 0; p2 < 4; ++p2) {
            pv[2*p2]   = bton((unsigned short)(pw[p2] & 0xFFFFu)) * invZ;
            pv[2*p2+1] = bton((unsigned short)(pw[p2] >> 16)) * invZ;
          }
          int bm = c * 512 + lane * 8;
          if (use_pg) {
            int w0 = 0, w1 = 0;
            w0 = __builtin_amdgcn_cvt_pk_fp8_f32(pv[0], pv[1], w0, false);
            w0 = __builtin_amdgcn_cvt_pk_fp8_f32(pv[2], pv[3], w0, true);
            w1 = __builtin_amdgcn_cvt_pk_fp8_f32(pv[4], pv[5], w1, false);
            w1 = __builtin_amdgcn_cvt_pk_fp8_f32(pv[6], pv[7], w1, true);
            uint2 wv; wv.x = (unsigned)w0; wv.y = (unsigned)w1;
            *(uint2*)(Pg + ((size_t)h * 4096 + (n0 + r)) * MPAD + bm) = wv;
          } else {
            float* base = attn_mean_out + (size_t)(n0 + r) * M2 + bm;
            #pragma unroll
            for (int k = 0; k < 8; ++k) {
              int m = bm + k;
              if (m < M2) {
                float v = pv[k] * 0.125f;
                if (h == 0) base[k] = v; else base[k] += v;
              }
            }
          }
        }
      }
    }
    __syncthreads();   // all waves' e finalized before PV reads all rows

    // ---- ph3: PV = e @ V (132 k-slices over 8 waves); scale by invZ in epilogue ----
    {
      f32x4 o0 = {0.f,0.f,0.f,0.f}, o1 = o0, o2 = o0, o3 = o0;
      const unsigned short* Vb = Vt + (size_t)(h * HD) * MPAD;
      const int nks = (w < 4) ? 17 : 16;
      const int ks0 = (w < 4) ? w * 17 : 68 + (w - 4) * 16;
      for (int ks = 0; ks < nks; ++ks) {
        int kk = (ks0 + ks) * 32 + lg * 8;
        bf16x8 a = *(const bf16x8*)(dsm + lrc * SROWB + ((2 * kk) ^ (lrc << 4)));
        {
          bf16x8 b0 = *(const bf16x8*)(Vb + (size_t)(lr) * MPAD + kk);
          bf16x8 b1 = *(const bf16x8*)(Vb + (size_t)(16 + lr) * MPAD + kk);
          o0 = __builtin_amdgcn_mfma_f32_16x16x32_bf16(a, b0, o0, 0, 0, 0);
          o1 = __builtin_amdgcn_mfma_f32_16x16x32_bf16(a, b1, o1, 0, 0, 0);
        }
        {
          bf16x8 b2 = *(const bf16x8*)(Vb + (size_t)(32 + lr) * MPAD + kk);
          bf16x8 b3 = *(const bf16x8*)(Vb + (size_t)(48 + lr) * MPAD + kk);
          o2 = __builtin_amdgcn_mfma_f32_16x16x32_bf16(a, b2, o2, 0, 0, 0);
          o3 = __builtin_amdgcn_mfma_f32_16x16x32_bf16(a, b3, o3, 0, 0, 0);
        }
      }
      __syncthreads();   // all waves done reading e
      float* part = (float*)dsm;   // [8 waves][16 rows][64] = 32 KB, overlays S rows
      #pragma unroll
      for (int q = 0; q < 4; q++) {
        int row = lg * 4 + q;
        part[w * 1024 + row * 64 +      lr] = o0[q];
        part[w * 1024 + row * 64 + 16 + lr] = o1[q];
        part[w * 1024 + row * 64 + 32 + lr] = o2[q];
        part[w * 1024 + row * 64 + 48 + lr] = o3[q];
      }
      __syncthreads();
      {
        float s = 0.f;
        #pragma unroll
        for (int ww = 0; ww < 8; ++ww) s += part[ww * 1024 + (t >> 6) * 64 + (t & 63)];
        aobf[(size_t)(n0 + (t >> 6)) * DIM + h * HD + (t & 63)] = btrunc(s * invZ);
      }
      // next head's post-ph0 barrier protects part reads from S overwrite
    }
  }
}

// ---------------- attn_mean = (1/8) sum_h fp8(Pg) ----------------
__global__ __launch_bounds__(256) void pg_reduce(
    const unsigned char* __restrict__ Pg, float* __restrict__ outA) {
  int tid = blockIdx.x * 256 + threadIdx.x;   // 4096 * 513 exactly
  int n = tid / 513, cm = tid % 513;
  int bm = cm * 8;
  float s[8] = {};
  #pragma unroll
  for (int h = 0; h < 8; ++h) {
    uint2 v = *(const uint2*)(Pg + ((size_t)h * 4096 + n) * MPAD + bm);
    s[0] += __builtin_amdgcn_cvt_f32_fp8((int)v.x, 0);
    s[1] += __builtin_amdgcn_cvt_f32_fp8((int)v.x, 1);
    s[2] += __builtin_amdgcn_cvt_f32_fp8((int)v.x, 2);
    s[3] += __builtin_amdgcn_cvt_f32_fp8((int)v.x, 3);
    s[4] += __builtin_amdgcn_cvt_f32_fp8((int)v.y, 0);
    s[5] += __builtin_amdgcn_cvt_f32_fp8((int)v.y, 1);
    s[6] += __builtin_amdgcn_cvt_f32_fp8((int)v.y, 2);
    s[7] += __builtin_amdgcn_cvt_f32_fp8((int)v.y, 3);
  }
  float* dst = outA + (size_t)n * M2 + bm;
  #pragma unroll
  for (int k = 0; k < 8; ++k)
    if (bm + k < M2) dst[k] = s[k] * 0.125f;
}

// ---------------- concat(sfbf, bf16(pj)) ----------------
__global__ __launch_bounds__(256) void cat_bf(
    const unsigned short* __restrict__ sfbf, const float* __restrict__ pj,
    unsigned short* __restrict__ cat) {
  int i4 = blockIdx.x * 256 + threadIdx.x;
  if (i4 >= (4096 * 1024) / 4) return;
  int idx = i4 * 4;
  int n = idx >> 10, c = idx & 1023;
  if (c < 512) {
    *(ushort4*)(cat + idx) = *(const ushort4*)(sfbf + (size_t)n * 512 + c);
  } else {
    float4 v = *(const float4*)(pj + (size_t)n * 512 + (c - 512));
    ushort4 o; o.x = btrunc(v.x); o.y = btrunc(v.y); o.z = btrunc(v.z); o.w = btrunc(v.w);
    *(ushort4*)(cat + idx) = o;
  }
}

// ---------------- gate, residual, RMSNorm, gate partial sums ----------------
__global__ __launch_bounds__(256) void final_kernel(
    const float* __restrict__ sf, const float* __restrict__ pj,
    const float* __restrict__ gl, const float* __restrict__ norm_w,
    float* __restrict__ outf, float* __restrict__ gpart) {
  int n = blockIdx.x, t = threadIdx.x;
  __shared__ float red[256];
  size_t base = (size_t)n * 512;
  float g0 = sigmoidf_(gl[base + t]);
  float g1 = sigmoidf_(gl[base + 256 + t]);
  float x0 = sf[base + t], x1 = sf[base + 256 + t];
  float p0 = pj[base + t], p1 = pj[base + 256 + t];
  float gr0 = x0 + g0 * p0, gr1 = x1 + g1 * p1;

  red[t] = g0 + g1;
  __syncthreads();
  for (int off = 128; off > 0; off >>= 1) {
    if (t < off) red[t] += red[t + off];
    __syncthreads();
  }
  if (t == 0) gpart[n] = red[0];
  __syncthreads();

  red[t] = gr0 * gr0 + gr1 * gr1;
  __syncthreads();
  for (int off = 128; off > 0; off >>= 1) {
    if (t < off) red[t] += red[t + off];
    __syncthreads();
  }
  float rms = rsqrtf(red[0] * (1.0f / 512.0f) + 1e-6f);
  outf[base + t] = gr0 * rms * norm_w[t];
  outf[base + 256 + t] = gr1 * rms * norm_w[256 + t];
}

__global__ __launch_bounds__(256) void gate_reduce(
    const float* __restrict__ gpart, float* __restrict__ out_scalar) {
  __shared__ float red[256];
  int t = threadIdx.x;
  float s = 0.f;
  for (int i = t; i < 4096; i += 256) s += gpart[i];
  red[t] = s;
  __syncthreads();
  for (int off = 128; off > 0; off >>= 1) {
    if (t < off) red[t] += red[t + off];
    __syncthreads();
  }
  if (t == 0) out_scalar[0] = red[0] * (1.0f / (4096.0f * 512.0f));
}

extern "C" void kernel_launch(void* const* d_in, const int* in_sizes, int n_in,
                              void* d_out, int out_size, void* d_ws, size_t ws_size,
                              hipStream_t stream) {
  const float* sf  = (const float*)d_in[0];
  const float* zp  = (const float*)d_in[1];
  const float* zs  = (const float*)d_in[2];
  const float* Wq  = (const float*)d_in[3];
  const float* Wk  = (const float*)d_in[4];
  const float* Wv  = (const float*)d_in[5];
  const float* Wg  = (const float*)d_in[6];
  const float* bg  = (const float*)d_in[7];
  const float* Wag = (const float*)d_in[8];
  const float* bag = (const float*)d_in[9];
  const float* nw  = (const float*)d_in[10];
  const float* Wo  = (const float*)d_in[11];
  const float* bo  = (const float*)d_in[12];

  float* out  = (float*)d_out;
  float* outF = out + OUT_F;
  float* outR = out + OUT_R;
  float* outG = out + OUT_G;
  float* outA = out + OUT_A;

  // workspace layout (bytes)
  char* W = (char*)d_ws;
  float*          regime  = (float*)(W + 0);                 // 2048
  float*          gpart   = (float*)(W + 2048);              // 16384
  unsigned short* sfbf    = (unsigned short*)(W + 18432);    // 4,194,304
  unsigned short* nodesbf = (unsigned short*)(W + 4212736);  // 4,196,352
  unsigned short* Qbf     = (unsigned short*)(W + 8409088);  // 4,194,304
  unsigned short* Kbf     = (unsigned short*)(W + 12603392); // 4,325,376 (4224 rows)
  unsigned short* Vt      = (unsigned short*)(W + 16928768); // 4,325,376 (512 x 4224)
  unsigned short* aobf    = (unsigned short*)(W + 21254144); // 4,194,304
  unsigned short* catbf   = (unsigned short*)(W + 25448448); // 8,388,608
  unsigned short* Wqbf    = (unsigned short*)(W + 33837056); // 524,288
  unsigned short* Wkbf    = (unsigned short*)(W + 34361344); // 524,288
  unsigned short* Wvbf    = (unsigned short*)(W + 34885632); // 524,288
  unsigned short* Wobf    = (unsigned short*)(W + 35409920); // 524,288
  unsigned short* Wagbf   = (unsigned short*)(W + 35934208); // 1,048,576
  float*          pj      = (float*)(W + 36982784);          // 8,388,608 -> 45,371,392
  float*          gl      = (float*)(W + 4212736);           // alias over nodesbf+Qbf (dead by then)
  unsigned char*  Pg      = (unsigned char*)(W + 45371392);  // 8*4096*4224 = 138,412,032
  const size_t need_pg = 45371392ull + (size_t)8 * 4096 * MPAD;
  const int use_pg = (ws_size >= need_pg) ? 1 : 0;

  hipFuncSetAttribute((const void*)fused_attn,
                      hipFuncAttributeMaxDynamicSharedMemorySize, SMEMSZ);

  // --- small prep ---
  regime_kernel<<<1, 256, 0, stream>>>(zp, zs, Wg, bg, regime);
  conv_bf<<<2048, 256, 0, stream>>>(sf, sfbf, 524288);
  build_nodes_bf<<<2049, 256, 0, stream>>>(zp, zs, sf, nodesbf);
  conv_bf<<<256, 256, 0, stream>>>(Wq, Wqbf, 65536);
  conv_bf<<<256, 256, 0, stream>>>(Wk, Wkbf, 65536);
  conv_bf<<<256, 256, 0, stream>>>(Wv, Wvbf, 65536);
  conv_bf<<<256, 256, 0, stream>>>(Wo, Wobf, 65536);
  conv_bf<<<512, 256, 0, stream>>>(Wag, Wagbf, 131072);
  hipMemsetAsync(Kbf, 0, 4325376, stream);
  hipMemsetAsync(Vt, 0, 4325376, stream);

  // --- projections (bf16 MFMA) ---
  gemm_bf16<<<dim3(4, 32), 256, 0, stream>>>(sfbf, Wqbf, nullptr, regime, nullptr, Qbf,
                                             4096, 512, 512, 512, 512, 512, 1.0f, 1);
  gemm_bf16<<<dim3(4, 33), 256, 0, stream>>>(nodesbf, Wkbf, nullptr, nullptr, nullptr, Kbf,
                                             M2, 512, 512, 512, 512, 512, 1.0f, 1);
  gemm_bf16<<<dim3(4, 33), 256, 0, stream>>>(nodesbf, Wvbf, nullptr, nullptr, nullptr, Vt,
                                             M2, 512, 512, 512, 512, MPAD, 1.0f, 2);

  // --- raw_scores = (Q @ K^T) * (0.125/8) over full 512 dims ---
  gemm_bf16<<<dim3(33, 32), 256, 0, stream>>>(Qbf, Kbf, nullptr, nullptr, outR, nullptr,
                                              4096, M2, 512, 512, 512, M2, 0.015625f, 0);

  // --- fused attention (512 blocks x 512 threads, 2 blocks/CU) ---
  fused_attn<<<512, 512, SMEMSZ, stream>>>(Qbf, Kbf, Vt, aobf, outA, Pg, use_pg);
  if (use_pg)
    pg_reduce<<<8208, 256, 0, stream>>>(Pg, outA);

  // --- output projection + gate + final ---
  gemm_bf16<<<dim3(4, 32), 256, 0, stream>>>(aobf, Wobf, bo, nullptr, pj, nullptr,
                                             4096, 512, 512, 512, 512, 512, 1.0f, 0);
  cat_bf<<<4096, 256, 0, stream>>>(sfbf, pj, catbf);
  gemm_bf16<<<dim3(4, 32), 256, 0, stream>>>(catbf, Wagbf, bag, nullptr, gl, nullptr,
                                             4096, 512, 1024, 1024, 1024, 512, 1.0f, 0);
  final_kernel<<<4096, 256, 0, stream>>>(sf, pj, gl, nw, outF, gpart);
  gate_reduce<<<1, 256, 0, stream>>>(gpart, outG);
}

// Round 14
// 1243.770 us; speedup vs baseline: 1.1571x; 1.1571x over previous
//
#include <hip/hip_runtime.h>
#include <hip/hip_fp16.h>
#include <math.h>

// Problem constants
#define NS 4096      // N stocks
#define DIM 512      // D
#define NH 8         // heads
#define HD 64        // head dim
#define M2 4098      // N + 2 nodes
#define MPAD 4224    // m padded to multiple of 32 (264 frags of 16)
#define KKEEP 2048u  // top-k keep

// Output layout (floats): final_out | raw_scores | gate_mean | attn_mean
#define OUT_F 0
#define OUT_R 2097152          // 4096*512
#define OUT_G 18882560         // + 4096*4098
#define OUT_A 18882561

typedef __attribute__((ext_vector_type(8))) short bf16x8;
typedef __attribute__((ext_vector_type(4))) float f32x4;

__device__ __forceinline__ float sigmoidf_(float x) { return 1.0f / (1.0f + __expf(-x)); }

__device__ __forceinline__ unsigned short btrunc(float f) {   // f32 -> bf16 RNE
  unsigned u = __float_as_uint(f);
  u = u + 0x7FFFu + ((u >> 16) & 1u);
  return (unsigned short)(u >> 16);
}
__device__ __forceinline__ float bton(unsigned short h) {
  return __uint_as_float(((unsigned)h) << 16);
}

// wave suffix-scan over 256 bins (4/lane) and rank pick; returns bin + count-strictly-above
__device__ __forceinline__ void scan_pick(unsigned c0, unsigned c1, unsigned c2, unsigned c3,
                                          unsigned k_rem, int lane,
                                          unsigned& bsel_out, unsigned& nxt_out) {
  unsigned run = c0 + c1 + c2 + c3;
  #pragma unroll
  for (int off = 1; off < 64; off <<= 1) {
    unsigned o_ = __shfl_down(run, off, 64);
    if (lane + off < 64) run += o_;
  }
  unsigned s0 = run, s1 = run - c0, s2 = s1 - c1, s3 = s2 - c2, s4 = s3 - c3;
  int which = -1;
  if      (s0 >= k_rem && s1 < k_rem) which = 0;
  else if (s1 >= k_rem && s2 < k_rem) which = 1;
  else if (s2 >= k_rem && s3 < k_rem) which = 2;
  else if (s3 >= k_rem && s4 < k_rem) which = 3;
  unsigned long long bal = __ballot(which >= 0);
  int src = (int)__ffsll(bal) - 1;
  unsigned nxtv = (which == 0) ? s1 : (which == 1) ? s2 : (which == 2) ? s3 : s4;
  unsigned bsel = (unsigned)(4 * lane + (which < 0 ? 0 : which));
  bsel_out = (unsigned)__shfl((int)bsel, src, 64);
  nxt_out  = (unsigned)__shfl((int)nxtv, src, 64);
}

// ---------------- regime_mod = sigmoid([zp,zs] @ Wg.T + bg) ----------------
__global__ __launch_bounds__(256) void regime_kernel(
    const float* __restrict__ zp, const float* __restrict__ zs,
    const float* __restrict__ Wg, const float* __restrict__ bg,
    float* __restrict__ regime) {
  __shared__ float zc[1024];
  int t = threadIdx.x;
  for (int i = t; i < 512; i += 256) { zc[i] = zp[i]; zc[512 + i] = zs[i]; }
  __syncthreads();
  for (int j = t; j < 512; j += 256) {
    const float4* w = (const float4*)(Wg + (size_t)j * 1024);
    float acc = 0.f;
    #pragma unroll 8
    for (int i = 0; i < 256; i++) {
      float4 wv = w[i];
      acc += wv.x * zc[4*i] + wv.y * zc[4*i+1] + wv.z * zc[4*i+2] + wv.w * zc[4*i+3];
    }
    regime[j] = sigmoidf_(acc + bg[j]);
  }
}

// ---------------- generic f32 -> bf16 convert ----------------
__global__ __launch_bounds__(256) void conv_bf(
    const float* __restrict__ src, unsigned short* __restrict__ dst, int n4) {
  int i4 = blockIdx.x * 256 + threadIdx.x;
  if (i4 >= n4) return;
  float4 v = *(const float4*)(src + (size_t)i4 * 4);
  ushort4 o; o.x = btrunc(v.x); o.y = btrunc(v.y); o.z = btrunc(v.z); o.w = btrunc(v.w);
  *(ushort4*)(dst + (size_t)i4 * 4) = o;
}

// ---------------- nodes = concat(zp, zs, sf) in bf16 ----------------
__global__ __launch_bounds__(256) void build_nodes_bf(
    const float* __restrict__ zp, const float* __restrict__ zs,
    const float* __restrict__ sf, unsigned short* __restrict__ nb) {
  int i4 = blockIdx.x * 256 + threadIdx.x;
  if (i4 >= (M2 * DIM) / 4) return;
  int idx = i4 * 4;
  int m = idx >> 9, c = idx & 511;
  const float* src = (m == 0) ? (zp + c) : (m == 1) ? (zs + c)
                               : (sf + (size_t)(m - 2) * 512 + c);
  float4 v = *(const float4*)src;
  ushort4 o; o.x = btrunc(v.x); o.y = btrunc(v.y); o.z = btrunc(v.z); o.w = btrunc(v.w);
  *(ushort4*)(nb + idx) = o;
}

// ---------------- bf16 MFMA GEMM: C = (A[M][K] @ B[N][K]^T * scale + bias) * cscale ----------------
// 128x128 tile, 256 threads (4 waves in 2x2), BK=32.
// mode 0: C fp32 [M][ldc]; mode 1: C bf16 [M][ldc]; mode 2: C bf16 transposed [N][ldc] (C[col][row]).
#define LSTR 40
__global__ __launch_bounds__(256) void gemm_bf16(
    const unsigned short* __restrict__ A, const unsigned short* __restrict__ B,
    const float* __restrict__ bias, const float* __restrict__ cscale,
    float* __restrict__ Cf, unsigned short* __restrict__ Cb,
    int M, int N, int K, int lda, int ldb, int ldc, float scale, int mode) {
  __shared__ unsigned short As[128 * LSTR];
  __shared__ unsigned short Bs[128 * LSTR];
  const int t = threadIdx.x;
  const int w = t >> 6, lane = t & 63;
  const int wr = w >> 1, wc = w & 1;
  const int lr = lane & 15, lg = lane >> 4;
  const int bm = blockIdx.y * 128, bn = blockIdx.x * 128;
  f32x4 acc[4][4] = {};
  for (int k0 = 0; k0 < K; k0 += 32) {
    #pragma unroll
    for (int i = 0; i < 2; i++) {
      int q = t + i * 256;
      int row = q >> 2;
      int ko = (q & 3) * 8;
      bf16x8 av = {};
      int gr = bm + row;
      if (gr < M) av = *(const bf16x8*)(A + (size_t)gr * lda + k0 + ko);
      *(bf16x8*)(As + row * LSTR + ko) = av;
      bf16x8 bv = {};
      int gbr = bn + row;
      if (gbr < N) bv = *(const bf16x8*)(B + (size_t)gbr * ldb + k0 + ko);
      *(bf16x8*)(Bs + row * LSTR + ko) = bv;
    }
    __syncthreads();
    {
      bf16x8 af[4], bfr[4];
      #pragma unroll
      for (int i = 0; i < 4; i++)
        af[i] = *(const bf16x8*)(As + (64 * wr + 16 * i + lr) * LSTR + lg * 8);
      #pragma unroll
      for (int j = 0; j < 4; j++)
        bfr[j] = *(const bf16x8*)(Bs + (64 * wc + 16 * j + lr) * LSTR + lg * 8);
      #pragma unroll
      for (int i = 0; i < 4; i++)
        #pragma unroll
        for (int j = 0; j < 4; j++)
          acc[i][j] = __builtin_amdgcn_mfma_f32_16x16x32_bf16(af[i], bfr[j], acc[i][j], 0, 0, 0);
    }
    __syncthreads();
  }
  // epilogue
  #pragma unroll
  for (int i = 0; i < 4; i++) {
    #pragma unroll
    for (int j = 0; j < 4; j++) {
      #pragma unroll
      for (int q = 0; q < 4; q++) {
        int row = bm + 64 * wr + 16 * i + lg * 4 + q;
        int col = bn + 64 * wc + 16 * j + lr;
        if (row < M && col < N) {
          float v = acc[i][j][q] * scale;
          if (bias)   v += bias[col];
          if (cscale) v *= cscale[col];
          if (mode == 0)      Cf[(size_t)row * ldc + col] = v;
          else if (mode == 1) Cb[(size_t)row * ldc + col] = btrunc(v);
          else                Cb[(size_t)col * ldc + row] = btrunc(v);
        }
      }
    }
  }
}

// ---------------- fused attention ----------------
// 256 blocks (16-row tile, 1/CU), 1024 threads = 16 waves, loop h=0..7.
// ph1: QK^T MFMA -> MONOTONE KEYS in swizzled LDS (pads/anchors stored as key 0;
//      anchor keys in side array) -> ph2 sweeps need NO per-element bounds checks.
// ph2 (3 sweeps, wave-private): pass0 (hi-byte hist + packed max), pass1
//   (boundary bin), exp sweep (e bf16 -> LDS  AND  fp8 e -> Pg, fused).
//   invZ -> Zg global; normalization happens in pg_reduce. Zero persistent state.
// ph3: PV MFMA K-split on raw e, scaled by invZ in epilogue; LDS reduce.
#define SROWB 8464                    // 8448 data + 16 pad
#define QOFF  (16 * SROWB)            // 135424
#define HOFF  (QOFF + 16 * 72 * 2)    // + 2304 = 137728
#define AOFF  (HOFF + 16 * 256 * 4)   // + 16384 = 154112
#define SMEMSZ (AOFF + 64)            // + 64 (anchor keys 16x2 u16) = 154176

__global__ __launch_bounds__(1024) void fused_attn(
    const unsigned short* __restrict__ Qbf, const unsigned short* __restrict__ Kbf,
    const unsigned short* __restrict__ Vt, unsigned short* __restrict__ aobf,
    float* __restrict__ attn_mean_out, unsigned char* __restrict__ Pg,
    float* __restrict__ Zg, int use_pg) {
  extern __shared__ char dsm[];
  unsigned short* qt = (unsigned short*)(dsm + QOFF);
  unsigned* hist = (unsigned*)(dsm + HOFF);          // [16 waves][256]
  unsigned short* anchk = (unsigned short*)(dsm + AOFF);  // [16 rows][2]
  const int n0 = blockIdx.x * 16;
  const int t = threadIdx.x;
  const int w = t >> 6, lane = t & 63;
  const int lr = lane & 15, lg = lane >> 4;
  unsigned* hw = hist + w * 256;
  const int r = w;                              // row owned by this wave
  const unsigned swz = (unsigned)((r & 7) << 4);

  for (int h = 0; h < NH; ++h) {
    // ---- ph0: Q tile -> LDS (16 x 64, stride 72) ----
    qt[(t >> 6) * 72 + (t & 63)] = Qbf[(size_t)(n0 + (t >> 6)) * DIM + h * HD + (t & 63)];
    __syncthreads();

    // ---- ph1: S keys -> LDS (swizzled); pads/anchors = 0; anchor keys aside ----
    {
      bf16x8 a0 = *(const bf16x8*)(qt + lr * 72 + lg * 8);
      bf16x8 a1 = *(const bf16x8*)(qt + lr * 72 + 32 + lg * 8);
      #pragma unroll
      for (int f = 0; f < 17; ++f) {
        if (f < 16 || w < 8) {                 // fi < 264
          int m0 = (w + 16 * f) * 16;
          const unsigned short* kp = Kbf + (size_t)(m0 + lr) * DIM + h * HD + lg * 8;
          bf16x8 b0 = *(const bf16x8*)(kp);
          bf16x8 b1 = *(const bf16x8*)(kp + 32);
          f32x4 c = {0.f, 0.f, 0.f, 0.f};
          c = __builtin_amdgcn_mfma_f32_16x16x32_bf16(a0, b0, c, 0, 0, 0);
          c = __builtin_amdgcn_mfma_f32_16x16x32_bf16(a1, b1, c, 0, 0, 0);
          int m = m0 + lr;
          #pragma unroll
          for (int q = 0; q < 4; ++q) {
            int rr = lg * 4 + q;
            unsigned short us = btrunc(c[q] * 0.125f);
            unsigned key = (unsigned)us ^ ((us & 0x8000u) ? 0xFFFFu : 0x8000u);
            unsigned short stor = (m >= M2 || m < 2) ? (unsigned short)0 : (unsigned short)key;
            *(unsigned short*)(dsm + rr * SROWB + ((2 * m) ^ ((rr & 7) << 4))) = stor;
            if (m < 2) anchk[rr * 2 + m] = (unsigned short)key;
          }
        }
      }
    }
    __syncthreads();

    // ---- ph2: 3-sweep select + exp for row r = w ----
    float invZ;
    {
      // pass 0: hi-byte histogram + max (no bounds checks; pads/anchors = key 0)
      unsigned maxkey = 0;
      hw[lane] = 0u; hw[lane + 64] = 0u; hw[lane + 128] = 0u; hw[lane + 192] = 0u;
      #pragma unroll
      for (int c = 0; c < 9; ++c) {
        if (c < 8 || lane < 16) {
          uint4 pk4 = *(const uint4*)(dsm + r * SROWB + (((unsigned)(c * 1024 + lane * 16)) ^ swz));
          const unsigned* pw = (const unsigned*)&pk4;
          #pragma unroll
          for (int p2 = 0; p2 < 4; ++p2) {
            unsigned pk = pw[p2];
            unsigned lo = pk & 0xFFFFu, hi = pk >> 16;
            atomicAdd(&hw[lo >> 8], 1u);
            atomicAdd(&hw[hi >> 8], 1u);
            if (lo > maxkey) maxkey = lo;
            if (hi > maxkey) maxkey = hi;
          }
        }
      }
      #pragma unroll
      for (int off = 32; off > 0; off >>= 1) {
        unsigned o_ = (unsigned)__shfl_xor((int)maxkey, off, 64);
        if (o_ > maxkey) maxkey = o_;
      }
      {
        unsigned a0 = anchk[2 * r], a1 = anchk[2 * r + 1];
        if (a0 > maxkey) maxkey = a0;
        if (a1 > maxkey) maxkey = a1;
      }
      float lmax = bton((unsigned short)(maxkey ^ ((maxkey & 0x8000u) ? 0x8000u : 0xFFFFu)));

      unsigned tb, k_rem = KKEEP;
      {
        // bin 0 holds pads/anchors (key 0) too, but threshold rank never reaches it
        unsigned c0 = hw[4*lane], c1 = hw[4*lane+1], c2 = hw[4*lane+2], c3 = hw[4*lane+3];
        unsigned nxtv;
        scan_pick(c0, c1, c2, c3, k_rem, lane, tb, nxtv);
        k_rem -= nxtv;
      }

      // pass 1: boundary-bin low-byte histogram
      hw[lane] = 0u; hw[lane + 64] = 0u; hw[lane + 128] = 0u; hw[lane + 192] = 0u;
      #pragma unroll
      for (int c = 0; c < 9; ++c) {
        if (c < 8 || lane < 16) {
          uint4 pk4 = *(const uint4*)(dsm + r * SROWB + (((unsigned)(c * 1024 + lane * 16)) ^ swz));
          const unsigned* pw = (const unsigned*)&pk4;
          #pragma unroll
          for (int p2 = 0; p2 < 4; ++p2) {
            unsigned pk = pw[p2];
            unsigned lo = pk & 0xFFFFu, hi = pk >> 16;
            if ((lo >> 8) == tb) atomicAdd(&hw[lo & 255u], 1u);
            if ((hi >> 8) == tb) atomicAdd(&hw[hi & 255u], 1u);
          }
        }
      }
      unsigned thrkey;
      {
        unsigned c0 = hw[4*lane], c1 = hw[4*lane+1], c2 = hw[4*lane+2], c3 = hw[4*lane+3];
        unsigned bsel, nxtv;
        scan_pick(c0, c1, c2, c3, k_rem, lane, bsel, nxtv);
        thrkey = (tb << 8) | bsel;
      }

      // exp sweep: e (bf16) -> LDS in place AND fp8 e -> Pg; lsum of rounded e
      float lsum = 0.f;
      #pragma unroll
      for (int c = 0; c < 9; ++c) {
        if (c < 8 || lane < 16) {
          char* ap = dsm + r * SROWB + (((unsigned)(c * 1024 + lane * 16)) ^ swz);
          uint4 pk4 = *(const uint4*)ap;
          unsigned* pw = (unsigned*)&pk4;
          float ev[8];
          #pragma unroll
          for (int p2 = 0; p2 < 4; ++p2) {
            unsigned pk = pw[p2];
            bool anc = (c == 0 && lane == 0 && p2 == 0);
            if (anc) pk = (unsigned)anchk[2 * r] | ((unsigned)anchk[2 * r + 1] << 16);
            unsigned outw = 0;
            #pragma unroll
            for (int e = 0; e < 2; ++e) {
              unsigned key = (e == 0) ? (pk & 0xFFFFu) : (pk >> 16);
              bool kept = anc || (key >= thrkey);
              unsigned short us = (unsigned short)(key ^ ((key & 0x8000u) ? 0x8000u : 0xFFFFu));
              float evf = kept ? __expf(bton(us) - lmax) : 0.f;
              unsigned short eb = btrunc(evf);
              float ef = bton(eb);
              lsum += ef;
              ev[2 * p2 + e] = ef;
              outw |= ((unsigned)eb) << (16 * e);
            }
            pw[p2] = outw;
          }
          *(uint4*)ap = pk4;
          if (use_pg) {
            int w0 = 0, w1 = 0;
            w0 = __builtin_amdgcn_cvt_pk_fp8_f32(ev[0], ev[1], w0, false);
            w0 = __builtin_amdgcn_cvt_pk_fp8_f32(ev[2], ev[3], w0, true);
            w1 = __builtin_amdgcn_cvt_pk_fp8_f32(ev[4], ev[5], w1, false);
            w1 = __builtin_amdgcn_cvt_pk_fp8_f32(ev[6], ev[7], w1, true);
            uint2 wv; wv.x = (unsigned)w0; wv.y = (unsigned)w1;
            *(uint2*)(Pg + ((size_t)h * 4096 + (n0 + r)) * MPAD + c * 512 + lane * 8) = wv;
          }
        }
      }
      #pragma unroll
      for (int off = 32; off > 0; off >>= 1) lsum += __shfl_xor(lsum, off, 64);
      invZ = 1.0f / lsum;
      if (use_pg) {
        if (lane == 0) Zg[h * 4096 + n0 + r] = invZ;
      } else {
        // fallback: fp32 RMW of attn_mean (extra sweep)
        for (int c = 0; c < 9; ++c) {
          if (c < 8 || lane < 16) {
            const char* ap = dsm + r * SROWB + (((unsigned)(c * 1024 + lane * 16)) ^ swz);
            uint4 e4 = *(const uint4*)ap;
            const unsigned* pw = (const unsigned*)&e4;
            int bm = c * 512 + lane * 8;
            float* base = attn_mean_out + (size_t)(n0 + r) * M2 + bm;
            #pragma unroll
            for (int p2 = 0; p2 < 4; ++p2) {
              float v0 = bton((unsigned short)(pw[p2] & 0xFFFFu)) * invZ * 0.125f;
              float v1 = bton((unsigned short)(pw[p2] >> 16)) * invZ * 0.125f;
              int m = bm + 2 * p2;
              if (m < M2)     { if (h == 0) base[2*p2] = v0;   else base[2*p2] += v0; }
              if (m + 1 < M2) { if (h == 0) base[2*p2+1] = v1; else base[2*p2+1] += v1; }
            }
          }
        }
      }
    }
    __syncthreads();   // all waves' e finalized before PV reads all rows

    // ---- ph3: PV = e @ V (K-split, slice s = w + 16*ks); scale by invZ in epilogue ----
    {
      f32x4 o0 = {0.f,0.f,0.f,0.f}, o1 = o0, o2 = o0, o3 = o0;
      const unsigned short* Vb = Vt + (size_t)(h * HD) * MPAD;
      #pragma unroll
      for (int ks = 0; ks < 9; ++ks) {
        if (ks < 8 || w < 4) {                 // slice < 132
          int kk = (w + 16 * ks) * 32 + lg * 8;
          bf16x8 a = *(const bf16x8*)(dsm + lr * SROWB + ((2 * kk) ^ ((lr & 7) << 4)));
          {
            bf16x8 b0 = *(const bf16x8*)(Vb + (size_t)(lr) * MPAD + kk);
            bf16x8 b1 = *(const bf16x8*)(Vb + (size_t)(16 + lr) * MPAD + kk);
            o0 = __builtin_amdgcn_mfma_f32_16x16x32_bf16(a, b0, o0, 0, 0, 0);
            o1 = __builtin_amdgcn_mfma_f32_16x16x32_bf16(a, b1, o1, 0, 0, 0);
          }
          {
            bf16x8 b2 = *(const bf16x8*)(Vb + (size_t)(32 + lr) * MPAD + kk);
            bf16x8 b3 = *(const bf16x8*)(Vb + (size_t)(48 + lr) * MPAD + kk);
            o2 = __builtin_amdgcn_mfma_f32_16x16x32_bf16(a, b2, o2, 0, 0, 0);
            o3 = __builtin_amdgcn_mfma_f32_16x16x32_bf16(a, b3, o3, 0, 0, 0);
          }
        }
      }
      __syncthreads();   // all waves done reading e
      float* part = (float*)dsm;   // [16][16][64] = 64 KB, overlays S rows
      #pragma unroll
      for (int q = 0; q < 4; q++) {
        int row = lg * 4 + q;
        part[w * 1024 + row * 64 +      lr] = o0[q];
        part[w * 1024 + row * 64 + 16 + lr] = o1[q];
        part[w * 1024 + row * 64 + 32 + lr] = o2[q];
        part[w * 1024 + row * 64 + 48 + lr] = o3[q];
      }
      __syncthreads();
      {
        float s = 0.f;
        #pragma unroll
        for (int ww = 0; ww < 16; ++ww) s += part[ww * 1024 + t];
        aobf[(size_t)(n0 + (t >> 6)) * DIM + h * HD + (t & 63)] = btrunc(s * invZ);
      }
      // next head's post-ph0 barrier protects part reads from S overwrite
    }
  }
}

// ---------------- attn_mean = (1/8) sum_h fp8(Pg) * Zinv[h][n] ----------------
__global__ __launch_bounds__(256) void pg_reduce(
    const unsigned char* __restrict__ Pg, const float* __restrict__ Zg,
    float* __restrict__ outA) {
  int tid = blockIdx.x * 256 + threadIdx.x;   // 4096 * 513 exactly
  int n = tid / 513, cm = tid % 513;
  int bm = cm * 8;
  float s[8] = {};
  #pragma unroll
  for (int h = 0; h < 8; ++h) {
    float zi = Zg[h * 4096 + n];
    uint2 v = *(const uint2*)(Pg + ((size_t)h * 4096 + n) * MPAD + bm);
    s[0] += __builtin_amdgcn_cvt_f32_fp8((int)v.x, 0) * zi;
    s[1] += __builtin_amdgcn_cvt_f32_fp8((int)v.x, 1) * zi;
    s[2] += __builtin_amdgcn_cvt_f32_fp8((int)v.x, 2) * zi;
    s[3] += __builtin_amdgcn_cvt_f32_fp8((int)v.x, 3) * zi;
    s[4] += __builtin_amdgcn_cvt_f32_fp8((int)v.y, 0) * zi;
    s[5] += __builtin_amdgcn_cvt_f32_fp8((int)v.y, 1) * zi;
    s[6] += __builtin_amdgcn_cvt_f32_fp8((int)v.y, 2) * zi;
    s[7] += __builtin_amdgcn_cvt_f32_fp8((int)v.y, 3) * zi;
  }
  float* dst = outA + (size_t)n * M2 + bm;
  #pragma unroll
  for (int k = 0; k < 8; ++k)
    if (bm + k < M2) dst[k] = s[k] * 0.125f;
}

// ---------------- concat(sfbf, bf16(pj)) ----------------
__global__ __launch_bounds__(256) void cat_bf(
    const unsigned short* __restrict__ sfbf, const float* __restrict__ pj,
    unsigned short* __restrict__ cat) {
  int i4 = blockIdx.x * 256 + threadIdx.x;
  if (i4 >= (4096 * 1024) / 4) return;
  int idx = i4 * 4;
  int n = idx >> 10, c = idx & 1023;
  if (c < 512) {
    *(ushort4*)(cat + idx) = *(const ushort4*)(sfbf + (size_t)n * 512 + c);
  } else {
    float4 v = *(const float4*)(pj + (size_t)n * 512 + (c - 512));
    ushort4 o; o.x = btrunc(v.x); o.y = btrunc(v.y); o.z = btrunc(v.z); o.w = btrunc(v.w);
    *(ushort4*)(cat + idx) = o;
  }
}

// ---------------- gate, residual, RMSNorm, gate partial sums ----------------
__global__ __launch_bounds__(256) void final_kernel(
    const float* __restrict__ sf, const float* __restrict__ pj,
    const float* __restrict__ gl, const float* __restrict__ norm_w,
    float* __restrict__ outf, float* __restrict__ gpart) {
  int n = blockIdx.x, t = threadIdx.x;
  __shared__ float red[256];
  size_t base = (size_t)n * 512;
  float g0 = sigmoidf_(gl[base + t]);
  float g1 = sigmoidf_(gl[base + 256 + t]);
  float x0 = sf[base + t], x1 = sf[base + 256 + t];
  float p0 = pj[base + t], p1 = pj[base + 256 + t];
  float gr0 = x0 + g0 * p0, gr1 = x1 + g1 * p1;

  red[t] = g0 + g1;
  __syncthreads();
  for (int off = 128; off > 0; off >>= 1) {
    if (t < off) red[t] += red[t + off];
    __syncthreads();
  }
  if (t == 0) gpart[n] = red[0];
  __syncthreads();

  red[t] = gr0 * gr0 + gr1 * gr1;
  __syncthreads();
  for (int off = 128; off > 0; off >>= 1) {
    if (t < off) red[t] += red[t + off];
    __syncthreads();
  }
  float rms = rsqrtf(red[0] * (1.0f / 512.0f) + 1e-6f);
  outf[base + t] = gr0 * rms * norm_w[t];
  outf[base + 256 + t] = gr1 * rms * norm_w[256 + t];
}

__global__ __launch_bounds__(256) void gate_reduce(
    const float* __restrict__ gpart, float* __restrict__ out_scalar) {
  __shared__ float red[256];
  int t = threadIdx.x;
  float s = 0.f;
  for (int i = t; i < 4096; i += 256) s += gpart[i];
  red[t] = s;
  __syncthreads();
  for (int off = 128; off > 0; off >>= 1) {
    if (t < off) red[t] += red[t + off];
    __syncthreads();
  }
  if (t == 0) out_scalar[0] = red[0] * (1.0f / (4096.0f * 512.0f));
}

extern "C" void kernel_launch(void* const* d_in, const int* in_sizes, int n_in,
                              void* d_out, int out_size, void* d_ws, size_t ws_size,
                              hipStream_t stream) {
  const float* sf  = (const float*)d_in[0];
  const float* zp  = (const float*)d_in[1];
  const float* zs  = (const float*)d_in[2];
  const float* Wq  = (const float*)d_in[3];
  const float* Wk  = (const float*)d_in[4];
  const float* Wv  = (const float*)d_in[5];
  const float* Wg  = (const float*)d_in[6];
  const float* bg  = (const float*)d_in[7];
  const float* Wag = (const float*)d_in[8];
  const float* bag = (const float*)d_in[9];
  const float* nw  = (const float*)d_in[10];
  const float* Wo  = (const float*)d_in[11];
  const float* bo  = (const float*)d_in[12];

  float* out  = (float*)d_out;
  float* outF = out + OUT_F;
  float* outR = out + OUT_R;
  float* outG = out + OUT_G;
  float* outA = out + OUT_A;

  // workspace layout (bytes)
  char* W = (char*)d_ws;
  float*          regime  = (float*)(W + 0);                 // 2048
  float*          gpart   = (float*)(W + 2048);              // 16384
  unsigned short* sfbf    = (unsigned short*)(W + 18432);    // 4,194,304
  unsigned short* nodesbf = (unsigned short*)(W + 4212736);  // 4,196,352
  unsigned short* Qbf     = (unsigned short*)(W + 8409088);  // 4,194,304
  unsigned short* Kbf     = (unsigned short*)(W + 12603392); // 4,325,376 (4224 rows)
  unsigned short* Vt      = (unsigned short*)(W + 16928768); // 4,325,376 (512 x 4224)
  unsigned short* aobf    = (unsigned short*)(W + 21254144); // 4,194,304
  unsigned short* catbf   = (unsigned short*)(W + 25448448); // 8,388,608
  unsigned short* Wqbf    = (unsigned short*)(W + 33837056); // 524,288
  unsigned short* Wkbf    = (unsigned short*)(W + 34361344); // 524,288
  unsigned short* Wvbf    = (unsigned short*)(W + 34885632); // 524,288
  unsigned short* Wobf    = (unsigned short*)(W + 35409920); // 524,288
  unsigned short* Wagbf   = (unsigned short*)(W + 35934208); // 1,048,576
  float*          pj      = (float*)(W + 36982784);          // 8,388,608 -> 45,371,392
  float*          gl      = (float*)(W + 4212736);           // alias over nodesbf+Qbf (dead by then)
  unsigned char*  Pg      = (unsigned char*)(W + 45371392);  // 8*4096*4224 = 138,412,032
  float*          Zg      = (float*)(W + 183783424);         // 8*4096*4 = 131,072
  const size_t need_pg = 183783424ull + 131072ull;
  const int use_pg = (ws_size >= need_pg) ? 1 : 0;

  hipFuncSetAttribute((const void*)fused_attn,
                      hipFuncAttributeMaxDynamicSharedMemorySize, SMEMSZ);

  // --- small prep ---
  regime_kernel<<<1, 256, 0, stream>>>(zp, zs, Wg, bg, regime);
  conv_bf<<<2048, 256, 0, stream>>>(sf, sfbf, 524288);
  build_nodes_bf<<<2049, 256, 0, stream>>>(zp, zs, sf, nodesbf);
  conv_bf<<<256, 256, 0, stream>>>(Wq, Wqbf, 65536);
  conv_bf<<<256, 256, 0, stream>>>(Wk, Wkbf, 65536);
  conv_bf<<<256, 256, 0, stream>>>(Wv, Wvbf, 65536);
  conv_bf<<<256, 256, 0, stream>>>(Wo, Wobf, 65536);
  conv_bf<<<512, 256, 0, stream>>>(Wag, Wagbf, 131072);
  hipMemsetAsync(Kbf, 0, 4325376, stream);
  hipMemsetAsync(Vt, 0, 4325376, stream);

  // --- projections (bf16 MFMA) ---
  gemm_bf16<<<dim3(4, 32), 256, 0, stream>>>(sfbf, Wqbf, nullptr, regime, nullptr, Qbf,
                                             4096, 512, 512, 512, 512, 512, 1.0f, 1);
  gemm_bf16<<<dim3(4, 33), 256, 0, stream>>>(nodesbf, Wkbf, nullptr, nullptr, nullptr, Kbf,
                                             M2, 512, 512, 512, 512, 512, 1.0f, 1);
  gemm_bf16<<<dim3(4, 33), 256, 0, stream>>>(nodesbf, Wvbf, nullptr, nullptr, nullptr, Vt,
                                             M2, 512, 512, 512, 512, MPAD, 1.0f, 2);

  // --- raw_scores = (Q @ K^T) * (0.125/8) over full 512 dims ---
  gemm_bf16<<<dim3(33, 32), 256, 0, stream>>>(Qbf, Kbf, nullptr, nullptr, outR, nullptr,
                                              4096, M2, 512, 512, 512, M2, 0.015625f, 0);

  // --- fused attention (256 blocks, 1024 threads, zero persistent reg state) ---
  fused_attn<<<256, 1024, SMEMSZ, stream>>>(Qbf, Kbf, Vt, aobf, outA, Pg, Zg, use_pg);
  if (use_pg)
    pg_reduce<<<8208, 256, 0, stream>>>(Pg, Zg, outA);

  // --- output projection + gate + final ---
  gemm_bf16<<<dim3(4, 32), 256, 0, stream>>>(aobf, Wobf, bo, nullptr, pj, nullptr,
                                             4096, 512, 512, 512, 512, 512, 1.0f, 0);
  cat_bf<<<4096, 256, 0, stream>>>(sfbf, pj, catbf);
  gemm_bf16<<<dim3(4, 32), 256, 0, stream>>>(catbf, Wagbf, bag, nullptr, gl, nullptr,
                                             4096, 512, 1024, 1024, 1024, 512, 1.0f, 0);
  final_kernel<<<4096, 256, 0, stream>>>(sf, pj, gl, nw, outF, gpart);
  gate_reduce<<<1, 256, 0, stream>>>(gpart, outG);
}

// Round 15
// 911.739 us; speedup vs baseline: 1.5784x; 1.3642x over previous
//
#include <hip/hip_runtime.h>
#include <hip/hip_fp16.h>
#include <math.h>

// Problem constants
#define NS 4096      // N stocks
#define DIM 512      // D
#define NH 8         // heads
#define HD 64        // head dim
#define M2 4098      // N + 2 nodes
#define MPAD 4224    // m padded to multiple of 32
#define KKEEP 2048u  // top-k keep

// Output layout (floats): final_out | raw_scores | gate_mean | attn_mean
#define OUT_F 0
#define OUT_R 2097152          // 4096*512
#define OUT_G 18882560         // + 4096*4098
#define OUT_A 18882561

typedef __attribute__((ext_vector_type(8))) short bf16x8;
typedef __attribute__((ext_vector_type(4))) float f32x4;

__device__ __forceinline__ float sigmoidf_(float x) { return 1.0f / (1.0f + __expf(-x)); }

__device__ __forceinline__ unsigned short btrunc(float f) {   // f32 -> bf16 RNE
  unsigned u = __float_as_uint(f);
  u = u + 0x7FFFu + ((u >> 16) & 1u);
  return (unsigned short)(u >> 16);
}
__device__ __forceinline__ float bton(unsigned short h) {
  return __uint_as_float(((unsigned)h) << 16);
}

// wave suffix-scan over 256 bins (4/lane) and rank pick
__device__ __forceinline__ void scan_pick(unsigned c0, unsigned c1, unsigned c2, unsigned c3,
                                          unsigned k_rem, int lane,
                                          unsigned& bsel_out, unsigned& nxt_out) {
  unsigned run = c0 + c1 + c2 + c3;
  #pragma unroll
  for (int off = 1; off < 64; off <<= 1) {
    unsigned o_ = __shfl_down(run, off, 64);
    if (lane + off < 64) run += o_;
  }
  unsigned s0 = run, s1 = run - c0, s2 = s1 - c1, s3 = s2 - c2, s4 = s3 - c3;
  int which = -1;
  if      (s0 >= k_rem && s1 < k_rem) which = 0;
  else if (s1 >= k_rem && s2 < k_rem) which = 1;
  else if (s2 >= k_rem && s3 < k_rem) which = 2;
  else if (s3 >= k_rem && s4 < k_rem) which = 3;
  unsigned long long bal = __ballot(which >= 0);
  int src = (int)__ffsll(bal) - 1;
  unsigned nxtv = (which == 0) ? s1 : (which == 1) ? s2 : (which == 2) ? s3 : s4;
  unsigned bsel = (unsigned)(4 * lane + (which < 0 ? 0 : which));
  bsel_out = (unsigned)__shfl((int)bsel, src, 64);
  nxt_out  = (unsigned)__shfl((int)nxtv, src, 64);
}

// ---------------- regime_mod = sigmoid([zp,zs] @ Wg.T + bg) ----------------
__global__ __launch_bounds__(256) void regime_kernel(
    const float* __restrict__ zp, const float* __restrict__ zs,
    const float* __restrict__ Wg, const float* __restrict__ bg,
    float* __restrict__ regime) {
  __shared__ float zc[1024];
  int t = threadIdx.x;
  for (int i = t; i < 512; i += 256) { zc[i] = zp[i]; zc[512 + i] = zs[i]; }
  __syncthreads();
  for (int j = t; j < 512; j += 256) {
    const float4* w = (const float4*)(Wg + (size_t)j * 1024);
    float acc = 0.f;
    #pragma unroll 8
    for (int i = 0; i < 256; i++) {
      float4 wv = w[i];
      acc += wv.x * zc[4*i] + wv.y * zc[4*i+1] + wv.z * zc[4*i+2] + wv.w * zc[4*i+3];
    }
    regime[j] = sigmoidf_(acc + bg[j]);
  }
}

// ---------------- generic f32 -> bf16 convert ----------------
__global__ __launch_bounds__(256) void conv_bf(
    const float* __restrict__ src, unsigned short* __restrict__ dst, int n4) {
  int i4 = blockIdx.x * 256 + threadIdx.x;
  if (i4 >= n4) return;
  float4 v = *(const float4*)(src + (size_t)i4 * 4);
  ushort4 o; o.x = btrunc(v.x); o.y = btrunc(v.y); o.z = btrunc(v.z); o.w = btrunc(v.w);
  *(ushort4*)(dst + (size_t)i4 * 4) = o;
}

// ---------------- nodes = concat(zp, zs, sf) in bf16 ----------------
__global__ __launch_bounds__(256) void build_nodes_bf(
    const float* __restrict__ zp, const float* __restrict__ zs,
    const float* __restrict__ sf, unsigned short* __restrict__ nb) {
  int i4 = blockIdx.x * 256 + threadIdx.x;
  if (i4 >= (M2 * DIM) / 4) return;
  int idx = i4 * 4;
  int m = idx >> 9, c = idx & 511;
  const float* src = (m == 0) ? (zp + c) : (m == 1) ? (zs + c)
                               : (sf + (size_t)(m - 2) * 512 + c);
  float4 v = *(const float4*)src;
  ushort4 o; o.x = btrunc(v.x); o.y = btrunc(v.y); o.z = btrunc(v.z); o.w = btrunc(v.w);
  *(ushort4*)(nb + idx) = o;
}

// ---------------- bf16 MFMA GEMM with z-batch strides ----------------
// C = (A[M][K] @ B[N][K]^T * scale + bias) * cscale ; 128x128 tile, BK=32.
// mode 0: C fp32; mode 1: C bf16 [M][ldc]; mode 2: C bf16 transposed [N][ldc].
// Per blockIdx.z: A += z*sA, B += z*sB, C += z*sC (element offsets).
#define LSTR 40
__global__ __launch_bounds__(256) void gemm_bf16(
    const unsigned short* __restrict__ A, const unsigned short* __restrict__ B,
    const float* __restrict__ bias, const float* __restrict__ cscale,
    float* __restrict__ Cf, unsigned short* __restrict__ Cb,
    int M, int N, int K, int lda, int ldb, int ldc, float scale, int mode,
    size_t sA, size_t sB, size_t sC) {
  __shared__ unsigned short As[128 * LSTR];
  __shared__ unsigned short Bs[128 * LSTR];
  const int z = blockIdx.z;
  A += (size_t)z * sA;
  B += (size_t)z * sB;
  if (Cf) Cf += (size_t)z * sC;
  if (Cb) Cb += (size_t)z * sC;
  const int t = threadIdx.x;
  const int w = t >> 6, lane = t & 63;
  const int wr = w >> 1, wc = w & 1;
  const int lr = lane & 15, lg = lane >> 4;
  const int bm = blockIdx.y * 128, bn = blockIdx.x * 128;
  f32x4 acc[4][4] = {};
  for (int k0 = 0; k0 < K; k0 += 32) {
    #pragma unroll
    for (int i = 0; i < 2; i++) {
      int q = t + i * 256;
      int row = q >> 2;
      int ko = (q & 3) * 8;
      bf16x8 av = {};
      int gr = bm + row;
      if (gr < M) av = *(const bf16x8*)(A + (size_t)gr * lda + k0 + ko);
      *(bf16x8*)(As + row * LSTR + ko) = av;
      bf16x8 bv = {};
      int gbr = bn + row;
      if (gbr < N) bv = *(const bf16x8*)(B + (size_t)gbr * ldb + k0 + ko);
      *(bf16x8*)(Bs + row * LSTR + ko) = bv;
    }
    __syncthreads();
    {
      bf16x8 af[4], bfr[4];
      #pragma unroll
      for (int i = 0; i < 4; i++)
        af[i] = *(const bf16x8*)(As + (64 * wr + 16 * i + lr) * LSTR + lg * 8);
      #pragma unroll
      for (int j = 0; j < 4; j++)
        bfr[j] = *(const bf16x8*)(Bs + (64 * wc + 16 * j + lr) * LSTR + lg * 8);
      #pragma unroll
      for (int i = 0; i < 4; i++)
        #pragma unroll
        for (int j = 0; j < 4; j++)
          acc[i][j] = __builtin_amdgcn_mfma_f32_16x16x32_bf16(af[i], bfr[j], acc[i][j], 0, 0, 0);
    }
    __syncthreads();
  }
  #pragma unroll
  for (int i = 0; i < 4; i++) {
    #pragma unroll
    for (int j = 0; j < 4; j++) {
      #pragma unroll
      for (int q = 0; q < 4; q++) {
        int row = bm + 64 * wr + 16 * i + lg * 4 + q;
        int col = bn + 64 * wc + 16 * j + lr;
        if (row < M && col < N) {
          float v = acc[i][j][q] * scale;
          if (bias)   v += bias[col];
          if (cscale) v *= cscale[col];
          if (mode == 0)      Cf[(size_t)row * ldc + col] = v;
          else if (mode == 1) Cb[(size_t)row * ldc + col] = btrunc(v);
          else                Cb[(size_t)col * ldc + row] = btrunc(v);
        }
      }
    }
  }
}

// ---------------- select + softmax over S planes (wave-per-row, no barriers) ----------------
// 8192 blocks x 256 threads (4 waves). Wave w owns global row = bid*4+w of the
// S planes [8*4096][MPAD] bf16. Stages the row into LDS as monotone keys
// (pads/anchors zeroed; anchor keys in lane-0 regs), then: pass0 hist+max,
// pass1 boundary bin, exp sweep (e bf16 -> LDS), normalize sweep writing
// NORMALIZED P bf16 back in-place to global. Zero __syncthreads.
__global__ __launch_bounds__(256) void select_softmax(unsigned short* __restrict__ S) {
  __shared__ unsigned short keys[4][MPAD];
  __shared__ unsigned hist[4][256];
  const int w = threadIdx.x >> 6, lane = threadIdx.x & 63;
  const size_t row = (size_t)blockIdx.x * 4 + w;
  unsigned short* kr = keys[w];
  unsigned* hw = hist[w];
  unsigned short* g = S + row * MPAD;
  unsigned a0k = 0, a1k = 0;

  // stage + convert to monotone keys
  #pragma unroll
  for (int c = 0; c < 9; ++c) {
    if (c < 8 || lane < 16) {
      uint4 v = *(const uint4*)(g + c * 512 + lane * 8);
      unsigned* pv = (unsigned*)&v;
      int mb = c * 512 + lane * 8;
      #pragma unroll
      for (int p2 = 0; p2 < 4; ++p2) {
        unsigned pk = pv[p2], outw = 0;
        #pragma unroll
        for (int e = 0; e < 2; ++e) {
          int m = mb + 2 * p2 + e;
          unsigned u = (e == 0) ? (pk & 0xFFFFu) : (pk >> 16);
          unsigned key = u ^ ((u & 0x8000u) ? 0xFFFFu : 0x8000u);
          if (m < 2) { if (m == 0) a0k = key; else a1k = key; key = 0u; }
          else if (m >= M2) key = 0u;
          outw |= key << (16 * e);
        }
        *(unsigned*)(kr + mb + 2 * p2) = outw;
      }
    }
  }

  // pass0: hi-byte histogram + row max
  hw[lane] = 0u; hw[lane + 64] = 0u; hw[lane + 128] = 0u; hw[lane + 192] = 0u;
  unsigned maxkey = (lane == 0) ? ((a0k > a1k) ? a0k : a1k) : 0u;
  #pragma unroll
  for (int c = 0; c < 9; ++c) {
    if (c < 8 || lane < 16) {
      uint4 v = *(const uint4*)(kr + c * 512 + lane * 8);
      const unsigned* pv = (const unsigned*)&v;
      #pragma unroll
      for (int p2 = 0; p2 < 4; ++p2) {
        unsigned lo = pv[p2] & 0xFFFFu, hi = pv[p2] >> 16;
        atomicAdd(&hw[lo >> 8], 1u);
        atomicAdd(&hw[hi >> 8], 1u);
        if (lo > maxkey) maxkey = lo;
        if (hi > maxkey) maxkey = hi;
      }
    }
  }
  #pragma unroll
  for (int off = 32; off > 0; off >>= 1) {
    unsigned o_ = (unsigned)__shfl_xor((int)maxkey, off, 64);
    if (o_ > maxkey) maxkey = o_;
  }
  float lmax = bton((unsigned short)(maxkey ^ ((maxkey & 0x8000u) ? 0x8000u : 0xFFFFu)));

  unsigned tb, k_rem = KKEEP;
  {
    unsigned c0 = hw[4*lane], c1 = hw[4*lane+1], c2 = hw[4*lane+2], c3 = hw[4*lane+3];
    unsigned nxtv;
    scan_pick(c0, c1, c2, c3, k_rem, lane, tb, nxtv);
    k_rem -= nxtv;
  }

  // pass1: boundary-bin low-byte histogram
  hw[lane] = 0u; hw[lane + 64] = 0u; hw[lane + 128] = 0u; hw[lane + 192] = 0u;
  #pragma unroll
  for (int c = 0; c < 9; ++c) {
    if (c < 8 || lane < 16) {
      uint4 v = *(const uint4*)(kr + c * 512 + lane * 8);
      const unsigned* pv = (const unsigned*)&v;
      #pragma unroll
      for (int p2 = 0; p2 < 4; ++p2) {
        unsigned lo = pv[p2] & 0xFFFFu, hi = pv[p2] >> 16;
        if ((lo >> 8) == tb) atomicAdd(&hw[lo & 255u], 1u);
        if ((hi >> 8) == tb) atomicAdd(&hw[hi & 255u], 1u);
      }
    }
  }
  unsigned thrkey;
  {
    unsigned c0 = hw[4*lane], c1 = hw[4*lane+1], c2 = hw[4*lane+2], c3 = hw[4*lane+3];
    unsigned bsel, nxtv;
    scan_pick(c0, c1, c2, c3, k_rem, lane, bsel, nxtv);
    thrkey = (tb << 8) | bsel;
  }

  // exp sweep: e (bf16) -> LDS; lsum of rounded e
  float lsum = 0.f;
  #pragma unroll
  for (int c = 0; c < 9; ++c) {
    if (c < 8 || lane < 16) {
      uint4 v = *(const uint4*)(kr + c * 512 + lane * 8);
      unsigned* pv = (unsigned*)&v;
      #pragma unroll
      for (int p2 = 0; p2 < 4; ++p2) {
        unsigned pk = pv[p2], outw = 0;
        bool anc = (c == 0 && lane == 0 && p2 == 0);
        if (anc) pk = a0k | (a1k << 16);
        #pragma unroll
        for (int e = 0; e < 2; ++e) {
          unsigned key = (e == 0) ? (pk & 0xFFFFu) : (pk >> 16);
          bool kept = anc || (key >= thrkey);
          unsigned short us = (unsigned short)(key ^ ((key & 0x8000u) ? 0x8000u : 0xFFFFu));
          float ev = kept ? __expf(bton(us) - lmax) : 0.f;
          unsigned short eb = btrunc(ev);
          lsum += bton(eb);
          outw |= ((unsigned)eb) << (16 * e);
        }
        pv[p2] = outw;
      }
      *(uint4*)(kr + c * 512 + lane * 8) = v;
    }
  }
  #pragma unroll
  for (int off = 32; off > 0; off >>= 1) lsum += __shfl_xor(lsum, off, 64);
  float invZ = 1.0f / lsum;

  // normalize sweep: p = e * invZ (bf16) -> global, in place over S
  #pragma unroll
  for (int c = 0; c < 9; ++c) {
    if (c < 8 || lane < 16) {
      uint4 v = *(const uint4*)(kr + c * 512 + lane * 8);
      unsigned* pv = (unsigned*)&v;
      #pragma unroll
      for (int p2 = 0; p2 < 4; ++p2) {
        unsigned pk = pv[p2];
        float pf0 = bton((unsigned short)(pk & 0xFFFFu)) * invZ;
        float pf1 = bton((unsigned short)(pk >> 16)) * invZ;
        pv[p2] = (unsigned)btrunc(pf0) | (((unsigned)btrunc(pf1)) << 16);
      }
      *(uint4*)(g + c * 512 + lane * 8) = v;
    }
  }
}

// ---------------- attn_mean = (1/8) sum_h P[h][n][m] ----------------
__global__ __launch_bounds__(256) void am_reduce(
    const unsigned short* __restrict__ P, float* __restrict__ outA) {
  int tid = blockIdx.x * 256 + threadIdx.x;   // 4096 * 513 exactly
  int n = tid / 513, cm = tid % 513;
  int bm = cm * 8;
  float s[8] = {};
  #pragma unroll
  for (int h = 0; h < 8; ++h) {
    uint4 v = *(const uint4*)(P + ((size_t)h * 4096 + n) * MPAD + bm);
    const unsigned* pv = (const unsigned*)&v;
    #pragma unroll
    for (int p2 = 0; p2 < 4; ++p2) {
      s[2*p2]   += bton((unsigned short)(pv[p2] & 0xFFFFu));
      s[2*p2+1] += bton((unsigned short)(pv[p2] >> 16));
    }
  }
  float* dst = outA + (size_t)n * M2 + bm;
  #pragma unroll
  for (int k = 0; k < 8; ++k)
    if (bm + k < M2) dst[k] = s[k] * 0.125f;
}

// ================= FALLBACK PATH (round-14 fused kernel) =================
#define SROWB 8464
#define QOFF  (16 * SROWB)
#define HOFF  (QOFF + 16 * 72 * 2)
#define AOFF  (HOFF + 16 * 256 * 4)
#define SMEMSZ (AOFF + 64)

__global__ __launch_bounds__(1024) void fused_attn(
    const unsigned short* __restrict__ Qbf, const unsigned short* __restrict__ Kbf,
    const unsigned short* __restrict__ Vt, unsigned short* __restrict__ aobf,
    float* __restrict__ attn_mean_out) {
  extern __shared__ char dsm[];
  unsigned short* qt = (unsigned short*)(dsm + QOFF);
  unsigned* hist = (unsigned*)(dsm + HOFF);
  unsigned short* anchk = (unsigned short*)(dsm + AOFF);
  const int n0 = blockIdx.x * 16;
  const int t = threadIdx.x;
  const int w = t >> 6, lane = t & 63;
  const int lr = lane & 15, lg = lane >> 4;
  unsigned* hw = hist + w * 256;
  const int r = w;
  const unsigned swz = (unsigned)((r & 7) << 4);

  for (int h = 0; h < NH; ++h) {
    qt[(t >> 6) * 72 + (t & 63)] = Qbf[(size_t)(n0 + (t >> 6)) * DIM + h * HD + (t & 63)];
    __syncthreads();
    {
      bf16x8 a0 = *(const bf16x8*)(qt + lr * 72 + lg * 8);
      bf16x8 a1 = *(const bf16x8*)(qt + lr * 72 + 32 + lg * 8);
      #pragma unroll
      for (int f = 0; f < 17; ++f) {
        if (f < 16 || w < 8) {
          int m0 = (w + 16 * f) * 16;
          const unsigned short* kp = Kbf + (size_t)(m0 + lr) * DIM + h * HD + lg * 8;
          bf16x8 b0 = *(const bf16x8*)(kp);
          bf16x8 b1 = *(const bf16x8*)(kp + 32);
          f32x4 c = {0.f, 0.f, 0.f, 0.f};
          c = __builtin_amdgcn_mfma_f32_16x16x32_bf16(a0, b0, c, 0, 0, 0);
          c = __builtin_amdgcn_mfma_f32_16x16x32_bf16(a1, b1, c, 0, 0, 0);
          int m = m0 + lr;
          #pragma unroll
          for (int q = 0; q < 4; ++q) {
            int rr = lg * 4 + q;
            unsigned short us = btrunc(c[q] * 0.125f);
            unsigned key = (unsigned)us ^ ((us & 0x8000u) ? 0xFFFFu : 0x8000u);
            unsigned short stor = (m >= M2 || m < 2) ? (unsigned short)0 : (unsigned short)key;
            *(unsigned short*)(dsm + rr * SROWB + ((2 * m) ^ ((rr & 7) << 4))) = stor;
            if (m < 2) anchk[rr * 2 + m] = (unsigned short)key;
          }
        }
      }
    }
    __syncthreads();

    float invZ;
    {
      unsigned maxkey = 0;
      hw[lane] = 0u; hw[lane + 64] = 0u; hw[lane + 128] = 0u; hw[lane + 192] = 0u;
      #pragma unroll
      for (int c = 0; c < 9; ++c) {
        if (c < 8 || lane < 16) {
          uint4 pk4 = *(const uint4*)(dsm + r * SROWB + (((unsigned)(c * 1024 + lane * 16)) ^ swz));
          const unsigned* pw = (const unsigned*)&pk4;
          #pragma unroll
          for (int p2 = 0; p2 < 4; ++p2) {
            unsigned pk = pw[p2];
            unsigned lo = pk & 0xFFFFu, hi = pk >> 16;
            atomicAdd(&hw[lo >> 8], 1u);
            atomicAdd(&hw[hi >> 8], 1u);
            if (lo > maxkey) maxkey = lo;
            if (hi > maxkey) maxkey = hi;
          }
        }
      }
      #pragma unroll
      for (int off = 32; off > 0; off >>= 1) {
        unsigned o_ = (unsigned)__shfl_xor((int)maxkey, off, 64);
        if (o_ > maxkey) maxkey = o_;
      }
      {
        unsigned a0 = anchk[2 * r], a1 = anchk[2 * r + 1];
        if (a0 > maxkey) maxkey = a0;
        if (a1 > maxkey) maxkey = a1;
      }
      float lmax = bton((unsigned short)(maxkey ^ ((maxkey & 0x8000u) ? 0x8000u : 0xFFFFu)));

      unsigned tb, k_rem = KKEEP;
      {
        unsigned c0 = hw[4*lane], c1 = hw[4*lane+1], c2 = hw[4*lane+2], c3 = hw[4*lane+3];
        unsigned nxtv;
        scan_pick(c0, c1, c2, c3, k_rem, lane, tb, nxtv);
        k_rem -= nxtv;
      }
      hw[lane] = 0u; hw[lane + 64] = 0u; hw[lane + 128] = 0u; hw[lane + 192] = 0u;
      #pragma unroll
      for (int c = 0; c < 9; ++c) {
        if (c < 8 || lane < 16) {
          uint4 pk4 = *(const uint4*)(dsm + r * SROWB + (((unsigned)(c * 1024 + lane * 16)) ^ swz));
          const unsigned* pw = (const unsigned*)&pk4;
          #pragma unroll
          for (int p2 = 0; p2 < 4; ++p2) {
            unsigned pk = pw[p2];
            unsigned lo = pk & 0xFFFFu, hi = pk >> 16;
            if ((lo >> 8) == tb) atomicAdd(&hw[lo & 255u], 1u);
            if ((hi >> 8) == tb) atomicAdd(&hw[hi & 255u], 1u);
          }
        }
      }
      unsigned thrkey;
      {
        unsigned c0 = hw[4*lane], c1 = hw[4*lane+1], c2 = hw[4*lane+2], c3 = hw[4*lane+3];
        unsigned bsel, nxtv;
        scan_pick(c0, c1, c2, c3, k_rem, lane, bsel, nxtv);
        thrkey = (tb << 8) | bsel;
      }

      float lsum = 0.f;
      #pragma unroll
      for (int c = 0; c < 9; ++c) {
        if (c < 8 || lane < 16) {
          char* ap = dsm + r * SROWB + (((unsigned)(c * 1024 + lane * 16)) ^ swz);
          uint4 pk4 = *(const uint4*)ap;
          unsigned* pw = (unsigned*)&pk4;
          #pragma unroll
          for (int p2 = 0; p2 < 4; ++p2) {
            unsigned pk = pw[p2];
            bool anc = (c == 0 && lane == 0 && p2 == 0);
            if (anc) pk = (unsigned)anchk[2 * r] | ((unsigned)anchk[2 * r + 1] << 16);
            unsigned outw = 0;
            #pragma unroll
            for (int e = 0; e < 2; ++e) {
              unsigned key = (e == 0) ? (pk & 0xFFFFu) : (pk >> 16);
              bool kept = anc || (key >= thrkey);
              unsigned short us = (unsigned short)(key ^ ((key & 0x8000u) ? 0x8000u : 0xFFFFu));
              float evf = kept ? __expf(bton(us) - lmax) : 0.f;
              unsigned short eb = btrunc(evf);
              lsum += bton(eb);
              outw |= ((unsigned)eb) << (16 * e);
            }
            pw[p2] = outw;
          }
          *(uint4*)ap = pk4;
        }
      }
      #pragma unroll
      for (int off = 32; off > 0; off >>= 1) lsum += __shfl_xor(lsum, off, 64);
      invZ = 1.0f / lsum;
      // fp32 RMW of attn_mean
      for (int c = 0; c < 9; ++c) {
        if (c < 8 || lane < 16) {
          const char* ap = dsm + r * SROWB + (((unsigned)(c * 1024 + lane * 16)) ^ swz);
          uint4 e4 = *(const uint4*)ap;
          const unsigned* pw = (const unsigned*)&e4;
          int bm = c * 512 + lane * 8;
          float* base = attn_mean_out + (size_t)(n0 + r) * M2 + bm;
          #pragma unroll
          for (int p2 = 0; p2 < 4; ++p2) {
            float v0 = bton((unsigned short)(pw[p2] & 0xFFFFu)) * invZ * 0.125f;
            float v1 = bton((unsigned short)(pw[p2] >> 16)) * invZ * 0.125f;
            int m = bm + 2 * p2;
            if (m < M2)     { if (h == 0) base[2*p2] = v0;   else base[2*p2] += v0; }
            if (m + 1 < M2) { if (h == 0) base[2*p2+1] = v1; else base[2*p2+1] += v1; }
          }
        }
      }
    }
    __syncthreads();

    {
      f32x4 o0 = {0.f,0.f,0.f,0.f}, o1 = o0, o2 = o0, o3 = o0;
      const unsigned short* Vb = Vt + (size_t)(h * HD) * MPAD;
      #pragma unroll
      for (int ks = 0; ks < 9; ++ks) {
        if (ks < 8 || w < 4) {
          int kk = (w + 16 * ks) * 32 + lg * 8;
          bf16x8 a = *(const bf16x8*)(dsm + lr * SROWB + ((2 * kk) ^ ((lr & 7) << 4)));
          {
            bf16x8 b0 = *(const bf16x8*)(Vb + (size_t)(lr) * MPAD + kk);
            bf16x8 b1 = *(const bf16x8*)(Vb + (size_t)(16 + lr) * MPAD + kk);
            o0 = __builtin_amdgcn_mfma_f32_16x16x32_bf16(a, b0, o0, 0, 0, 0);
            o1 = __builtin_amdgcn_mfma_f32_16x16x32_bf16(a, b1, o1, 0, 0, 0);
          }
          {
            bf16x8 b2 = *(const bf16x8*)(Vb + (size_t)(32 + lr) * MPAD + kk);
            bf16x8 b3 = *(const bf16x8*)(Vb + (size_t)(48 + lr) * MPAD + kk);
            o2 = __builtin_amdgcn_mfma_f32_16x16x32_bf16(a, b2, o2, 0, 0, 0);
            o3 = __builtin_amdgcn_mfma_f32_16x16x32_bf16(a, b3, o3, 0, 0, 0);
          }
        }
      }
      __syncthreads();
      float* part = (float*)dsm;
      #pragma unroll
      for (int q = 0; q < 4; q++) {
        int row = lg * 4 + q;
        part[w * 1024 + row * 64 +      lr] = o0[q];
        part[w * 1024 + row * 64 + 16 + lr] = o1[q];
        part[w * 1024 + row * 64 + 32 + lr] = o2[q];
        part[w * 1024 + row * 64 + 48 + lr] = o3[q];
      }
      __syncthreads();
      {
        float s = 0.f;
        #pragma unroll
        for (int ww = 0; ww < 16; ++ww) s += part[ww * 1024 + t];
        aobf[(size_t)(n0 + (t >> 6)) * DIM + h * HD + (t & 63)] = btrunc(s * invZ);
      }
    }
  }
}

// ---------------- concat(sfbf, bf16(pj)) ----------------
__global__ __launch_bounds__(256) void cat_bf(
    const unsigned short* __restrict__ sfbf, const float* __restrict__ pj,
    unsigned short* __restrict__ cat) {
  int i4 = blockIdx.x * 256 + threadIdx.x;
  if (i4 >= (4096 * 1024) / 4) return;
  int idx = i4 * 4;
  int n = idx >> 10, c = idx & 1023;
  if (c < 512) {
    *(ushort4*)(cat + idx) = *(const ushort4*)(sfbf + (size_t)n * 512 + c);
  } else {
    float4 v = *(const float4*)(pj + (size_t)n * 512 + (c - 512));
    ushort4 o; o.x = btrunc(v.x); o.y = btrunc(v.y); o.z = btrunc(v.z); o.w = btrunc(v.w);
    *(ushort4*)(cat + idx) = o;
  }
}

// ---------------- gate, residual, RMSNorm, gate partial sums ----------------
__global__ __launch_bounds__(256) void final_kernel(
    const float* __restrict__ sf, const float* __restrict__ pj,
    const float* __restrict__ gl, const float* __restrict__ norm_w,
    float* __restrict__ outf, float* __restrict__ gpart) {
  int n = blockIdx.x, t = threadIdx.x;
  __shared__ float red[256];
  size_t base = (size_t)n * 512;
  float g0 = sigmoidf_(gl[base + t]);
  float g1 = sigmoidf_(gl[base + 256 + t]);
  float x0 = sf[base + t], x1 = sf[base + 256 + t];
  float p0 = pj[base + t], p1 = pj[base + 256 + t];
  float gr0 = x0 + g0 * p0, gr1 = x1 + g1 * p1;

  red[t] = g0 + g1;
  __syncthreads();
  for (int off = 128; off > 0; off >>= 1) {
    if (t < off) red[t] += red[t + off];
    __syncthreads();
  }
  if (t == 0) gpart[n] = red[0];
  __syncthreads();

  red[t] = gr0 * gr0 + gr1 * gr1;
  __syncthreads();
  for (int off = 128; off > 0; off >>= 1) {
    if (t < off) red[t] += red[t + off];
    __syncthreads();
  }
  float rms = rsqrtf(red[0] * (1.0f / 512.0f) + 1e-6f);
  outf[base + t] = gr0 * rms * norm_w[t];
  outf[base + 256 + t] = gr1 * rms * norm_w[256 + t];
}

__global__ __launch_bounds__(256) void gate_reduce(
    const float* __restrict__ gpart, float* __restrict__ out_scalar) {
  __shared__ float red[256];
  int t = threadIdx.x;
  float s = 0.f;
  for (int i = t; i < 4096; i += 256) s += gpart[i];
  red[t] = s;
  __syncthreads();
  for (int off = 128; off > 0; off >>= 1) {
    if (t < off) red[t] += red[t + off];
    __syncthreads();
  }
  if (t == 0) out_scalar[0] = red[0] * (1.0f / (4096.0f * 512.0f));
}

extern "C" void kernel_launch(void* const* d_in, const int* in_sizes, int n_in,
                              void* d_out, int out_size, void* d_ws, size_t ws_size,
                              hipStream_t stream) {
  const float* sf  = (const float*)d_in[0];
  const float* zp  = (const float*)d_in[1];
  const float* zs  = (const float*)d_in[2];
  const float* Wq  = (const float*)d_in[3];
  const float* Wk  = (const float*)d_in[4];
  const float* Wv  = (const float*)d_in[5];
  const float* Wg  = (const float*)d_in[6];
  const float* bg  = (const float*)d_in[7];
  const float* Wag = (const float*)d_in[8];
  const float* bag = (const float*)d_in[9];
  const float* nw  = (const float*)d_in[10];
  const float* Wo  = (const float*)d_in[11];
  const float* bo  = (const float*)d_in[12];

  float* out  = (float*)d_out;
  float* outF = out + OUT_F;
  float* outR = out + OUT_R;
  float* outG = out + OUT_G;
  float* outA = out + OUT_A;

  // workspace layout (bytes)
  char* W = (char*)d_ws;
  float*          regime  = (float*)(W + 0);                 // 2048
  float*          gpart   = (float*)(W + 2048);              // 16384
  unsigned short* sfbf    = (unsigned short*)(W + 18432);    // 4,194,304
  unsigned short* nodesbf = (unsigned short*)(W + 4212736);  // 4,196,352
  unsigned short* Qbf     = (unsigned short*)(W + 8409088);  // 4,194,304
  unsigned short* Kbf     = (unsigned short*)(W + 12603392); // 4,325,376
  unsigned short* Vt      = (unsigned short*)(W + 16928768); // 4,325,376 (512 x 4224)
  unsigned short* aobf    = (unsigned short*)(W + 21254144); // 4,194,304
  unsigned short* catbf   = (unsigned short*)(W + 25448448); // 8,388,608
  unsigned short* Wqbf    = (unsigned short*)(W + 33837056); // 524,288
  unsigned short* Wkbf    = (unsigned short*)(W + 34361344); // 524,288
  unsigned short* Wvbf    = (unsigned short*)(W + 34885632); // 524,288
  unsigned short* Wobf    = (unsigned short*)(W + 35409920); // 524,288
  unsigned short* Wagbf   = (unsigned short*)(W + 35934208); // 1,048,576
  float*          pj      = (float*)(W + 36982784);          // 8,388,608 -> 45,371,392
  float*          gl      = (float*)(W + 4212736);           // alias (dead by then)
  unsigned short* Splane  = (unsigned short*)(W + 45371392); // 8*4096*4224*2 = 276,824,064
  const size_t need_s = 45371392ull + (size_t)8 * 4096 * MPAD * 2;
  const int use_s = (ws_size >= need_s) ? 1 : 0;

  hipFuncSetAttribute((const void*)fused_attn,
                      hipFuncAttributeMaxDynamicSharedMemorySize, SMEMSZ);

  // --- small prep ---
  regime_kernel<<<1, 256, 0, stream>>>(zp, zs, Wg, bg, regime);
  conv_bf<<<2048, 256, 0, stream>>>(sf, sfbf, 524288);
  build_nodes_bf<<<2049, 256, 0, stream>>>(zp, zs, sf, nodesbf);
  conv_bf<<<256, 256, 0, stream>>>(Wq, Wqbf, 65536);
  conv_bf<<<256, 256, 0, stream>>>(Wk, Wkbf, 65536);
  conv_bf<<<256, 256, 0, stream>>>(Wv, Wvbf, 65536);
  conv_bf<<<256, 256, 0, stream>>>(Wo, Wobf, 65536);
  conv_bf<<<512, 256, 0, stream>>>(Wag, Wagbf, 131072);
  hipMemsetAsync(Kbf, 0, 4325376, stream);
  hipMemsetAsync(Vt, 0, 4325376, stream);

  // --- projections (bf16 MFMA) ---
  gemm_bf16<<<dim3(4, 32, 1), 256, 0, stream>>>(sfbf, Wqbf, nullptr, regime, nullptr, Qbf,
                                                4096, 512, 512, 512, 512, 512, 1.0f, 1, 0, 0, 0);
  gemm_bf16<<<dim3(4, 33, 1), 256, 0, stream>>>(nodesbf, Wkbf, nullptr, nullptr, nullptr, Kbf,
                                                M2, 512, 512, 512, 512, 512, 1.0f, 1, 0, 0, 0);
  gemm_bf16<<<dim3(4, 33, 1), 256, 0, stream>>>(nodesbf, Wvbf, nullptr, nullptr, nullptr, Vt,
                                                M2, 512, 512, 512, 512, MPAD, 1.0f, 2, 0, 0, 0);

  // --- raw_scores = (Q @ K^T) * (0.125/8) over full 512 dims ---
  gemm_bf16<<<dim3(33, 32, 1), 256, 0, stream>>>(Qbf, Kbf, nullptr, nullptr, outR, nullptr,
                                                 4096, M2, 512, 512, 512, M2, 0.015625f, 0, 0, 0, 0);

  if (use_s) {
    // --- S planes: S[h][n][m] = 0.125 * q_h(n) . k_h(m)  (batched over h) ---
    gemm_bf16<<<dim3(33, 32, 8), 256, 0, stream>>>(Qbf, Kbf, nullptr, nullptr, nullptr, Splane,
                                                   4096, M2, 64, 512, 512, MPAD, 0.125f, 1,
                                                   64, 64, (size_t)4096 * MPAD);
    // --- select + softmax (wave-per-row, barrier-free); P bf16 in-place ---
    select_softmax<<<8192, 256, 0, stream>>>(Splane);
    // --- PV: out[n, h*64+d] = sum_m P[h][n][m] * Vt[h*64+d][m] (batched) ---
    gemm_bf16<<<dim3(1, 32, 8), 256, 0, stream>>>(Splane, Vt, nullptr, nullptr, nullptr, aobf,
                                                  4096, 64, MPAD, MPAD, MPAD, 512, 1.0f, 1,
                                                  (size_t)4096 * MPAD, (size_t)64 * MPAD, 64);
    // --- attn_mean = mean over heads of P ---
    am_reduce<<<8208, 256, 0, stream>>>(Splane, outA);
  } else {
    fused_attn<<<256, 1024, SMEMSZ, stream>>>(Qbf, Kbf, Vt, aobf, outA);
  }

  // --- output projection + gate + final ---
  gemm_bf16<<<dim3(4, 32, 1), 256, 0, stream>>>(aobf, Wobf, bo, nullptr, pj, nullptr,
                                                4096, 512, 512, 512, 512, 512, 1.0f, 0, 0, 0, 0);
  cat_bf<<<4096, 256, 0, stream>>>(sfbf, pj, catbf);
  gemm_bf16<<<dim3(4, 32, 1), 256, 0, stream>>>(catbf, Wagbf, bag, nullptr, gl, nullptr,
                                                4096, 512, 1024, 1024, 1024, 512, 1.0f, 0, 0, 0, 0);
  final_kernel<<<4096, 256, 0, stream>>>(sf, pj, gl, nw, outF, gpart);
  gate_reduce<<<1, 256, 0, stream>>>(gpart, outG);
}